// Round 5
// baseline (1391.030 us; speedup 1.0000x reference)
//
#include <hip/hip_runtime.h>
#include <hip/hip_bf16.h>
#include <cstdint>
#include <cstddef>

// GuidedGNN: 3x GATConv(H=3, EMB=128, concat) + head transforms + MLP head.
// R4 (resubmit; prior run hit container infra failure): merged linear weights
// (Wh@Wnext precomputed on device) -> 4 big GEMMs; K templated (full unroll);
// pi-permuted channel layout -> 1x12B gather/edge; softmax denominators via
// atomics in k_ex (kills k_agg pass A); unroll x8.

#define F_IN 128
#define EMB  128
#define NH   3
#define HE   (NH*EMB)   // 384

typedef __attribute__((ext_vector_type(8))) short bf16x8;
typedef __attribute__((ext_vector_type(4))) float f32x4;

__device__ __forceinline__ float lrelu(float x){ return x > 0.f ? x : 0.2f * x; }
__device__ __forceinline__ float b2f(unsigned short u){ return __uint_as_float((unsigned)u << 16); }
__device__ __forceinline__ unsigned short f2b(float f){
  __hip_bfloat16 h = __float2bfloat16(f);
  return *reinterpret_cast<unsigned short*>(&h);
}
// channel permutation: orig c in [0,384) -> p*6 + head*2 + pos (lane-contiguous 12B groups)
__device__ __forceinline__ int pi(int c){
  int hh = c >> 7, w = c & 127;
  return (w >> 1) * 6 + hh * 2 + (w & 1);
}

struct u32x3 { unsigned x, y, z; };

// ---------------- CSR build ----------------
__global__ void k_hist(const int* __restrict__ ei, int E, int Nn, int* __restrict__ cnt){
  int total = E + Nn;
  for (int i = blockIdx.x * blockDim.x + threadIdx.x; i < total; i += gridDim.x * blockDim.x){
    int d = (i < E) ? ei[E + i] : (i - E);
    atomicAdd(&cnt[d], 1);
  }
}

__global__ void k_scan1(const int* __restrict__ cnt, int n, int* __restrict__ rs, int* __restrict__ bsum){
  __shared__ int s[256];
  int t = threadIdx.x;
  int i = blockIdx.x * 256 + t;
  int v = (i < n) ? cnt[i] : 0;
  s[t] = v; __syncthreads();
  for (int off = 1; off < 256; off <<= 1){
    int x = (t >= off) ? s[t - off] : 0;
    __syncthreads();
    s[t] += x;
    __syncthreads();
  }
  if (i < n) rs[i + 1] = s[t];
  if (t == 255) bsum[blockIdx.x] = s[255];
}

__global__ void k_scan2(int* __restrict__ bsum, int nb){
  __shared__ int s[256];
  int t = threadIdx.x;
  int v = (t < nb) ? bsum[t] : 0;
  s[t] = v; __syncthreads();
  for (int off = 1; off < 256; off <<= 1){
    int x = (t >= off) ? s[t - off] : 0;
    __syncthreads();
    s[t] += x;
    __syncthreads();
  }
  if (t < nb) bsum[t] = (t > 0) ? s[t - 1] : 0;  // exclusive
}

__global__ void k_scan3(int* __restrict__ rs, const int* __restrict__ bsum, int n){
  int i = blockIdx.x * 256 + threadIdx.x;
  if (i < n) rs[i + 1] += bsum[blockIdx.x];
  if (i == 0) rs[0] = 0;
}

__global__ void k_scatter(const int* __restrict__ ei, int E, int Nn, const int* __restrict__ rs,
                          int* __restrict__ fill, int* __restrict__ esrc, int* __restrict__ edst){
  int total = E + Nn;
  for (int i = blockIdx.x * blockDim.x + threadIdx.x; i < total; i += gridDim.x * blockDim.x){
    int s, d;
    if (i < E){ s = ei[i]; d = ei[E + i]; } else { s = i - E; d = s; }
    int pos = rs[d] + atomicAdd(&fill[d], 1);
    esrc[pos] = s;
    edst[pos] = d;
  }
}

// ---------------- dtype prep ----------------
__global__ void k_f2b4(const float* __restrict__ in, unsigned short* __restrict__ out, int n4){
  int i = blockIdx.x * blockDim.x + threadIdx.x;
  if (i >= n4) return;
  float4 v = reinterpret_cast<const float4*>(in)[i];
  unsigned short o[4] = {f2b(v.x), f2b(v.y), f2b(v.z), f2b(v.w)};
  *reinterpret_cast<uint2*>(&out[i * 4]) = *reinterpret_cast<uint2*>(o);
}

// W [K, Ncols] fp32 -> BT [Ncols, K] bf16
__global__ void k_w2bt(const float* __restrict__ W, unsigned short* __restrict__ BT, int K, int Ncols){
  int i = blockIdx.x * 256 + threadIdx.x;
  if (i >= K * Ncols) return;
  int r = i / Ncols, c = i % Ncols;
  BT[(size_t)c * K + r] = f2b(W[i]);
}

// merged bias: outv[c] = sum_k bh[k]*W[k,c] (+ badd[c])
__global__ void k_bvec(const float* __restrict__ bh, const float* __restrict__ W,
                       const float* __restrict__ badd, float* __restrict__ outv, int K, int C){
  int c = blockIdx.x * 256 + threadIdx.x;
  if (c >= C) return;
  float s = badd ? badd[c] : 0.f;
  for (int k = 0; k < K; ++k) s += bh[k] * W[(size_t)k * C + c];
  outv[c] = s;
}

// ---------------- MFMA GEMM: C[M,Ncols](bf16) = A[M,K](bf16) @ BT[Ncols,K]^T ----------------
// 128x128 tile, 4 waves, each 64x64 (4x4 frags of 16x16x32), frags direct from global.
// K compile-time -> full unroll. PERM: store cols pi-permuted (Ncols must be 384).
// a_s!=null: fused attention logits (Ncols==384, col-block==head).
template<int K, bool PERM>
__global__ __launch_bounds__(256) void k_mgemm(const unsigned short* __restrict__ A,
                                               const unsigned short* __restrict__ BT,
                                               const float* __restrict__ bias,
                                               unsigned short* __restrict__ C,
                                               const float* __restrict__ a_s,
                                               const float* __restrict__ a_d,
                                               float* __restrict__ als, float* __restrict__ ald,
                                               int M, int Ncols, int act){
  __shared__ float sred[2][128];
  __shared__ float dred[2][128];
  const int lane = threadIdx.x & 63;
  const int wave = threadIdx.x >> 6;
  const int brow = blockIdx.x * 128;
  const int row0 = brow + (wave >> 1) * 64;
  const int col0 = blockIdx.y * 128 + (wave & 1) * 64;
  const int r15 = lane & 15;
  const int kg = (lane >> 4) * 8;
  f32x4 acc[4][4] = {};
  int ar[4];
#pragma unroll
  for (int m = 0; m < 4; ++m){
    int r = row0 + m * 16 + r15;
    ar[m] = (r < M) ? r : (M - 1);
  }
#pragma unroll
  for (int kt = 0; kt < K; kt += 32){
    bf16x8 a[4], b[4];
#pragma unroll
    for (int m = 0; m < 4; ++m)
      a[m] = *reinterpret_cast<const bf16x8*>(&A[(size_t)ar[m] * K + kt + kg]);
#pragma unroll
    for (int n = 0; n < 4; ++n)
      b[n] = *reinterpret_cast<const bf16x8*>(&BT[(size_t)(col0 + n * 16 + r15) * K + kt + kg]);
#pragma unroll
    for (int m = 0; m < 4; ++m)
#pragma unroll
      for (int n = 0; n < 4; ++n)
        acc[m][n] = __builtin_amdgcn_mfma_f32_16x16x32_bf16(a[m], b[n], acc[m][n], 0, 0, 0);
  }
  // C store (bf16) + optional bias/elu; PERM permutes the stored column
#pragma unroll
  for (int m = 0; m < 4; ++m){
#pragma unroll
    for (int n = 0; n < 4; ++n){
      int c = col0 + n * 16 + r15;
      float bsv = bias ? bias[c] : 0.f;
      int cs = PERM ? pi(c) : c;
#pragma unroll
      for (int q = 0; q < 4; ++q){
        int r = row0 + m * 16 + (lane >> 4) * 4 + q;
        if (r < M){
          float v = acc[m][n][q] + bsv;
          if (act) v = (v > 0.f) ? v : expm1f(v);
          C[(size_t)r * Ncols + cs] = f2b(v);
        }
      }
    }
  }
  // fused attention logits (fp32 accumulators, full head dot within this block)
  if (a_s){
    const int head = blockIdx.y;
    const int cin = (wave & 1) * 64;
    float asv[4], adv[4];
#pragma unroll
    for (int n = 0; n < 4; ++n){
      int c = head * EMB + cin + n * 16 + r15;
      asv[n] = a_s[c]; adv[n] = a_d[c];
    }
#pragma unroll
    for (int m = 0; m < 4; ++m){
#pragma unroll
      for (int q = 0; q < 4; ++q){
        float ps = acc[m][0][q] * asv[0] + acc[m][1][q] * asv[1]
                 + acc[m][2][q] * asv[2] + acc[m][3][q] * asv[3];
        float pd = acc[m][0][q] * adv[0] + acc[m][1][q] * adv[1]
                 + acc[m][2][q] * adv[2] + acc[m][3][q] * adv[3];
#pragma unroll
        for (int off = 1; off < 16; off <<= 1){
          ps += __shfl_xor(ps, off);
          pd += __shfl_xor(pd, off);
        }
        if (r15 == 0){
          int rowl = (wave >> 1) * 64 + m * 16 + (lane >> 4) * 4 + q;
          sred[wave & 1][rowl] = ps;
          dred[wave & 1][rowl] = pd;
        }
      }
    }
    __syncthreads();
    if (threadIdx.x < 128){
      int rowl = threadIdx.x;
      int r = brow + rowl;
      if (r < M){
        als[(size_t)r * 3 + head] = sred[0][rowl] + sred[1][rowl];
        ald[(size_t)r * 3 + head] = dred[0][rowl] + dred[1][rowl];
      }
    }
  }
}

// ---------------- edge-parallel unnormalized attention weights + denom atomics ----------------
// softmax shift-invariant, |logit| O(1) by construction -> exp w/o max is safe in fp32.
__global__ void k_ex(const float* __restrict__ als, const float* __restrict__ ald,
                     const int* __restrict__ esrc, const int* __restrict__ edst,
                     float4* __restrict__ ex4, float* __restrict__ den, int total){
  int i = blockIdx.x * 256 + threadIdx.x;
  if (i >= total) return;
  int s = esrc[i], d = edst[i];
  float e0 = __expf(lrelu(als[s * 3 + 0] + ald[d * 3 + 0]));
  float e1 = __expf(lrelu(als[s * 3 + 1] + ald[d * 3 + 1]));
  float e2 = __expf(lrelu(als[s * 3 + 2] + ald[d * 3 + 2]));
  ex4[i] = make_float4(e0, e1, e2, 0.f);
  atomicAdd(&den[d * 3 + 0], e0);
  atomicAdd(&den[d * 3 + 1], e1);
  atomicAdd(&den[d * 3 + 2], e2);
}

// ---------------- GAT aggregation (one wave per dst node) + bias + elu -> bf16 ----
// h in pi layout: lane's 6 channels = bytes [lane*12, lane*12+12) = 3 dwords (head pairs).
__global__ __launch_bounds__(256) void k_agg(const unsigned short* __restrict__ h,
                                             const float4* __restrict__ ex4,
                                             const int* __restrict__ rs, const int* __restrict__ esrc,
                                             const float* __restrict__ den,
                                             const float* __restrict__ bias,
                                             unsigned short* __restrict__ out, int Nn){
  int n = blockIdx.x * 4 + (threadIdx.x >> 6);
  int lane = threadIdx.x & 63;
  if (n >= Nn) return;
  int start = rs[n], end = rs[n + 1];
  float inv0 = 1.f / (den[n * 3 + 0] + 1e-16f);
  float inv1 = 1.f / (den[n * 3 + 1] + 1e-16f);
  float inv2 = 1.f / (den[n * 3 + 2] + 1e-16f);
  float acc[6] = {0.f, 0.f, 0.f, 0.f, 0.f, 0.f};
  const int l3 = lane * 3;
  int i = start;
  for (; i + 7 < end; i += 8){
    u32x3 hv[8]; float4 ev[8];
#pragma unroll
    for (int u = 0; u < 8; ++u){
      int s = esrc[i + u];
      hv[u] = *reinterpret_cast<const u32x3*>(reinterpret_cast<const unsigned*>(h + (size_t)s * HE) + l3);
      ev[u] = ex4[i + u];
    }
#pragma unroll
    for (int u = 0; u < 8; ++u){
      acc[0] += ev[u].x * b2f((unsigned short)hv[u].x);
      acc[1] += ev[u].x * b2f((unsigned short)(hv[u].x >> 16));
      acc[2] += ev[u].y * b2f((unsigned short)hv[u].y);
      acc[3] += ev[u].y * b2f((unsigned short)(hv[u].y >> 16));
      acc[4] += ev[u].z * b2f((unsigned short)hv[u].z);
      acc[5] += ev[u].z * b2f((unsigned short)(hv[u].z >> 16));
    }
  }
  for (; i < end; ++i){
    int s = esrc[i];
    u32x3 v = *reinterpret_cast<const u32x3*>(reinterpret_cast<const unsigned*>(h + (size_t)s * HE) + l3);
    float4 e = ex4[i];
    acc[0] += e.x * b2f((unsigned short)v.x);
    acc[1] += e.x * b2f((unsigned short)(v.x >> 16));
    acc[2] += e.y * b2f((unsigned short)v.y);
    acc[3] += e.y * b2f((unsigned short)(v.y >> 16));
    acc[4] += e.z * b2f((unsigned short)v.z);
    acc[5] += e.z * b2f((unsigned short)(v.z >> 16));
  }
  float iv[3] = {inv0, inv1, inv2};
  unsigned ov[3];
#pragma unroll
  for (int hh = 0; hh < 3; ++hh){
    int ch = 128 * hh + 2 * lane;           // original channel ids for bias
    float v0 = acc[2 * hh] * iv[hh] + bias[ch];
    float v1 = acc[2 * hh + 1] * iv[hh] + bias[ch + 1];
    v0 = (v0 > 0.f) ? v0 : expm1f(v0);
    v1 = (v1 > 0.f) ? v1 : expm1f(v1);
    ov[hh] = (unsigned)f2b(v0) | ((unsigned)f2b(v1) << 16);
  }
  unsigned* orow = reinterpret_cast<unsigned*>(out + (size_t)n * HE) + l3;
  *reinterpret_cast<u32x3*>(orow) = *reinterpret_cast<u32x3*>(ov);   // pi layout
}

// ---------------- final dot: sigmoid(Z @ Wl2 + bl2), Z bf16 [N,512] ----------------
__global__ __launch_bounds__(256) void k_head(const unsigned short* __restrict__ Z,
                                              const float* __restrict__ w, const float* __restrict__ b,
                                              float* __restrict__ out, int Nn){
  int n = blockIdx.x * 4 + (threadIdx.x >> 6);
  int lane = threadIdx.x & 63;
  if (n >= Nn) return;
  const unsigned short* zr = Z + (size_t)n * 512;
  float sum = 0.f;
#pragma unroll
  for (int j = 0; j < 4; ++j){
    int ch = 128 * j + 2 * lane;
    unsigned v = *reinterpret_cast<const unsigned*>(&zr[ch]);
    sum += b2f((unsigned short)v) * w[ch] + b2f((unsigned short)(v >> 16)) * w[ch + 1];
  }
  for (int off = 32; off; off >>= 1) sum += __shfl_xor(sum, off);
  if (lane == 0) out[n] = 1.f / (1.f + __expf(-(sum + b[0])));
}

extern "C" void kernel_launch(void* const* d_in, const int* in_sizes, int n_in,
                              void* d_out, int out_size, void* d_ws, size_t ws_size,
                              hipStream_t stream){
  const float* x   = (const float*)d_in[0];
  const int*   ei  = (const int*)d_in[1];
  const int N = in_sizes[0] / F_IN;
  const int E = in_sizes[1] / 2;
  const float* W[3]  = {(const float*)d_in[2], (const float*)d_in[6], (const float*)d_in[10]};
  const float* AS[3] = {(const float*)d_in[3], (const float*)d_in[7], (const float*)d_in[11]};
  const float* AD[3] = {(const float*)d_in[4], (const float*)d_in[8], (const float*)d_in[12]};
  const float* BB[3] = {(const float*)d_in[5], (const float*)d_in[9], (const float*)d_in[13]};
  const float* WH[3] = {(const float*)d_in[14], (const float*)d_in[16], (const float*)d_in[18]};
  const float* BH[3] = {(const float*)d_in[15], (const float*)d_in[17], (const float*)d_in[19]};
  const float* Wl1 = (const float*)d_in[20];
  const float* bl1 = (const float*)d_in[21];
  const float* Wl2 = (const float*)d_in[22];
  const float* bl2 = (const float*)d_in[23];
  float* out = (float*)d_out;

  // ---- workspace layout ----
  char* ws = (char*)d_ws;
  size_t off = 0;
  auto alloc = [&](size_t bytes) -> char* {
    char* p = ws + off;
    off = (off + bytes + 255) & ~(size_t)255;
    return p;
  };
  int*   row_start = (int*)alloc((size_t)(N + 1) * 4);
  int*   fill      = (int*)alloc((size_t)N * 4);
  int*   esrc      = (int*)alloc((size_t)(E + N) * 4);
  int*   edst      = (int*)alloc((size_t)(E + N) * 4);
  int*   bsum      = (int*)alloc(256 * 4);
  float* als       = (float*)alloc((size_t)N * 3 * 4);
  float* ald       = (float*)alloc((size_t)N * 3 * 4);
  float* den       = (float*)alloc((size_t)N * 3 * 4);
  float4* ex4      = (float4*)alloc((size_t)(E + N) * 16);
  unsigned short* xb = (unsigned short*)alloc((size_t)N * F_IN * 2);   // x bf16
  unsigned short* P  = (unsigned short*)alloc((size_t)N * HE * 2);     // h [N,384] bf16 (pi layout)
  unsigned short* Q  = (unsigned short*)alloc((size_t)N * HE * 2);     // agg out bf16 (pi layout)
  unsigned short* Z  = (unsigned short*)alloc((size_t)N * 512 * 2);    // MLP hidden bf16
  // weight slabs
  unsigned short* W1T  = (unsigned short*)alloc((size_t)F_IN * HE * 2);  // [384,128]
  unsigned short* W2T  = (unsigned short*)alloc((size_t)F_IN * HE * 2);  // [384,128]
  unsigned short* W3T  = (unsigned short*)alloc((size_t)F_IN * HE * 2);  // [384,128]
  unsigned short* Wl1T = (unsigned short*)alloc((size_t)F_IN * 512 * 2); // [512,128]
  unsigned short* Wh1b = (unsigned short*)alloc((size_t)HE * F_IN * 2);  // [384,128] bf16 copy
  unsigned short* Wh2b = (unsigned short*)alloc((size_t)HE * F_IN * 2);
  unsigned short* Wh3b = (unsigned short*)alloc((size_t)HE * F_IN * 2);
  unsigned short* M2T  = (unsigned short*)alloc((size_t)HE * HE * 2);   // [384, 384] (K pi-permuted)
  unsigned short* M3T  = (unsigned short*)alloc((size_t)HE * HE * 2);
  unsigned short* M4T  = (unsigned short*)alloc((size_t)512 * HE * 2);  // [512, 384]
  float* c2 = (float*)alloc(HE * 4);
  float* c3 = (float*)alloc(HE * 4);
  float* c4 = (float*)alloc(512 * 4);

  // ---- CSR by dst (counting sort) ----
  hipMemsetAsync(fill, 0, (size_t)N * 4, stream);
  k_hist<<<2048, 256, 0, stream>>>(ei, E, N, fill);
  int nsb = (N + 255) / 256;
  k_scan1<<<nsb, 256, 0, stream>>>(fill, N, row_start, bsum);
  k_scan2<<<1, 256, 0, stream>>>(bsum, nsb);
  k_scan3<<<nsb, 256, 0, stream>>>(row_start, bsum, N);
  hipMemsetAsync(fill, 0, (size_t)N * 4, stream);
  k_scatter<<<2048, 256, 0, stream>>>(ei, E, N, row_start, fill, esrc, edst);

  // ---- dtype prep + merged weights ----
  k_f2b4<<<(N * F_IN / 4 + 255) / 256, 256, 0, stream>>>(x, xb, N * F_IN / 4);
  k_w2bt<<<(F_IN * HE + 255) / 256, 256, 0, stream>>>(W[0], W1T, F_IN, HE);
  k_w2bt<<<(F_IN * HE + 255) / 256, 256, 0, stream>>>(W[1], W2T, F_IN, HE);
  k_w2bt<<<(F_IN * HE + 255) / 256, 256, 0, stream>>>(W[2], W3T, F_IN, HE);
  k_w2bt<<<(F_IN * 512 + 255) / 256, 256, 0, stream>>>(Wl1, Wl1T, F_IN, 512);
  k_f2b4<<<(HE * F_IN / 4 + 255) / 256, 256, 0, stream>>>(WH[0], Wh1b, HE * F_IN / 4);
  k_f2b4<<<(HE * F_IN / 4 + 255) / 256, 256, 0, stream>>>(WH[1], Wh2b, HE * F_IN / 4);
  k_f2b4<<<(HE * F_IN / 4 + 255) / 256, 256, 0, stream>>>(WH[2], Wh3b, HE * F_IN / 4);
  // merged weights: M2T[c, pi(k)] = (Wh1@W2)[k,c]  (A=W2T, BT=Wh1b), etc.
  k_mgemm<128, true><<<dim3(3, 3), 256, 0, stream>>>(W2T, Wh1b, nullptr, M2T,
      nullptr, nullptr, nullptr, nullptr, HE, HE, 0);
  k_mgemm<128, true><<<dim3(3, 3), 256, 0, stream>>>(W3T, Wh2b, nullptr, M3T,
      nullptr, nullptr, nullptr, nullptr, HE, HE, 0);
  k_mgemm<128, true><<<dim3(4, 3), 256, 0, stream>>>(Wl1T, Wh3b, nullptr, M4T,
      nullptr, nullptr, nullptr, nullptr, 512, HE, 0);
  // merged biases
  k_bvec<<<2, 256, 0, stream>>>(BH[0], W[1], nullptr, c2, F_IN, HE);
  k_bvec<<<2, 256, 0, stream>>>(BH[1], W[2], nullptr, c3, F_IN, HE);
  k_bvec<<<2, 256, 0, stream>>>(BH[2], Wl1, bl1, c4, F_IN, 512);

  const int mb = (N + 127) / 128;
  const int nwave = (N + 3) / 4;
  const int tot = E + N;
  const int exg = (tot + 255) / 256;

  // ---- layer 1 ----
  k_mgemm<128, true><<<dim3(mb, 3), 256, 0, stream>>>(xb, W1T, nullptr, P,
      AS[0], AD[0], als, ald, N, HE, 0);
  hipMemsetAsync(den, 0, (size_t)N * 12, stream);
  k_ex<<<exg, 256, 0, stream>>>(als, ald, esrc, edst, ex4, den, tot);
  k_agg<<<nwave, 256, 0, stream>>>(P, ex4, row_start, esrc, den, BB[0], Q, N);
  // ---- layer 2 (head transform folded into M2T) ----
  k_mgemm<384, true><<<dim3(mb, 3), 256, 0, stream>>>(Q, M2T, c2, P,
      AS[1], AD[1], als, ald, N, HE, 0);
  hipMemsetAsync(den, 0, (size_t)N * 12, stream);
  k_ex<<<exg, 256, 0, stream>>>(als, ald, esrc, edst, ex4, den, tot);
  k_agg<<<nwave, 256, 0, stream>>>(P, ex4, row_start, esrc, den, BB[1], Q, N);
  // ---- layer 3 ----
  k_mgemm<384, true><<<dim3(mb, 3), 256, 0, stream>>>(Q, M3T, c3, P,
      AS[2], AD[2], als, ald, N, HE, 0);
  hipMemsetAsync(den, 0, (size_t)N * 12, stream);
  k_ex<<<exg, 256, 0, stream>>>(als, ald, esrc, edst, ex4, den, tot);
  k_agg<<<nwave, 256, 0, stream>>>(P, ex4, row_start, esrc, den, BB[2], Q, N);
  // ---- MLP (head transform 3 folded into M4T): Z = elu(Q @ M4T^T + c4) ----
  k_mgemm<384, false><<<dim3(mb, 4), 256, 0, stream>>>(Q, M4T, c4, Z,
      nullptr, nullptr, nullptr, nullptr, N, 512, 1);
  // out = sigmoid(Z @ Wl2 + bl2)
  k_head<<<nwave, 256, 0, stream>>>(Z, Wl2, bl2, out, N);
}

// Round 6
// 796.793 us; speedup vs baseline: 1.7458x; 1.7458x over previous
//
#include <hip/hip_runtime.h>
#include <hip/hip_bf16.h>
#include <cstdint>
#include <cstddef>

// GuidedGNN: 3x GATConv(H=3, EMB=128, concat) + head transforms + MLP head.
// R5: revert R4's two mistakes (edge-rate atomics -> memory-side RMW disaster;
// weight merge through rank-128 bottleneck -> MORE flops). Keep R4 wins:
// templated-K GEMMs, pi-permuted layout (1x12B gather/edge), k_agg unroll x8.
// Denominators via lane-parallel pass A in k_agg (R3-proven).

#define F_IN 128
#define EMB  128
#define NH   3
#define HE   (NH*EMB)   // 384

typedef __attribute__((ext_vector_type(8))) short bf16x8;
typedef __attribute__((ext_vector_type(4))) float f32x4;

__device__ __forceinline__ float lrelu(float x){ return x > 0.f ? x : 0.2f * x; }
__device__ __forceinline__ float b2f(unsigned short u){ return __uint_as_float((unsigned)u << 16); }
__device__ __forceinline__ unsigned short f2b(float f){
  __hip_bfloat16 h = __float2bfloat16(f);
  return *reinterpret_cast<unsigned short*>(&h);
}
// channel permutation: orig c in [0,384) -> (c%128/2)*6 + head*2 + (c&1)
__device__ __forceinline__ int pi(int c){
  int hh = c >> 7, w = c & 127;
  return (w >> 1) * 6 + hh * 2 + (w & 1);
}

struct u32x3 { unsigned x, y, z; };
struct f32x3 { float x, y, z; };

// ---------------- CSR build ----------------
__global__ void k_hist(const int* __restrict__ ei, int E, int Nn, int* __restrict__ cnt){
  int total = E + Nn;
  for (int i = blockIdx.x * blockDim.x + threadIdx.x; i < total; i += gridDim.x * blockDim.x){
    int d = (i < E) ? ei[E + i] : (i - E);
    atomicAdd(&cnt[d], 1);
  }
}

__global__ void k_scan1(const int* __restrict__ cnt, int n, int* __restrict__ rs, int* __restrict__ bsum){
  __shared__ int s[256];
  int t = threadIdx.x;
  int i = blockIdx.x * 256 + t;
  int v = (i < n) ? cnt[i] : 0;
  s[t] = v; __syncthreads();
  for (int off = 1; off < 256; off <<= 1){
    int x = (t >= off) ? s[t - off] : 0;
    __syncthreads();
    s[t] += x;
    __syncthreads();
  }
  if (i < n) rs[i + 1] = s[t];
  if (t == 255) bsum[blockIdx.x] = s[255];
}

__global__ void k_scan2(int* __restrict__ bsum, int nb){
  __shared__ int s[256];
  int t = threadIdx.x;
  int v = (t < nb) ? bsum[t] : 0;
  s[t] = v; __syncthreads();
  for (int off = 1; off < 256; off <<= 1){
    int x = (t >= off) ? s[t - off] : 0;
    __syncthreads();
    s[t] += x;
    __syncthreads();
  }
  if (t < nb) bsum[t] = (t > 0) ? s[t - 1] : 0;  // exclusive
}

__global__ void k_scan3(int* __restrict__ rs, const int* __restrict__ bsum, int n){
  int i = blockIdx.x * 256 + threadIdx.x;
  if (i < n) rs[i + 1] += bsum[blockIdx.x];
  if (i == 0) rs[0] = 0;
}

__global__ void k_scatter(const int* __restrict__ ei, int E, int Nn, const int* __restrict__ rs,
                          int* __restrict__ fill, int* __restrict__ esrc, int* __restrict__ edst){
  int total = E + Nn;
  for (int i = blockIdx.x * blockDim.x + threadIdx.x; i < total; i += gridDim.x * blockDim.x){
    int s, d;
    if (i < E){ s = ei[i]; d = ei[E + i]; } else { s = i - E; d = s; }
    int pos = rs[d] + atomicAdd(&fill[d], 1);
    esrc[pos] = s;
    edst[pos] = d;
  }
}

// ---------------- dtype prep ----------------
__global__ void k_f2b4(const float* __restrict__ in, unsigned short* __restrict__ out, int n4){
  int i = blockIdx.x * blockDim.x + threadIdx.x;
  if (i >= n4) return;
  float4 v = reinterpret_cast<const float4*>(in)[i];
  unsigned short o[4] = {f2b(v.x), f2b(v.y), f2b(v.z), f2b(v.w)};
  *reinterpret_cast<uint2*>(&out[i * 4]) = *reinterpret_cast<uint2*>(o);
}

// W [K, Ncols] fp32 -> BT [Ncols, K] bf16
__global__ void k_w2bt(const float* __restrict__ W, unsigned short* __restrict__ BT, int K, int Ncols){
  int i = blockIdx.x * 256 + threadIdx.x;
  if (i >= K * Ncols) return;
  int r = i / Ncols, c = i % Ncols;
  BT[(size_t)c * K + r] = f2b(W[i]);
}

// W [384, Ncols] fp32 -> BT [Ncols, 384] bf16 with K-dim pi-permuted
__global__ void k_w2btp(const float* __restrict__ W, unsigned short* __restrict__ BT, int Ncols){
  int i = blockIdx.x * 256 + threadIdx.x;
  if (i >= HE * Ncols) return;
  int r = i / Ncols, c = i % Ncols;
  BT[(size_t)c * HE + pi(r)] = f2b(W[i]);
}

// ---------------- MFMA GEMM: C[M,Ncols](bf16) = A[M,K](bf16) @ BT[Ncols,K]^T ----------------
// 128x128 tile, 4 waves, each 64x64 (4x4 frags of 16x16x32), frags direct from global.
// K compile-time -> full unroll. PERM: store cols pi-permuted (Ncols must be 384).
// a_s!=null: fused attention logits (Ncols==384, col-block==head).
template<int K, bool PERM>
__global__ __launch_bounds__(256) void k_mgemm(const unsigned short* __restrict__ A,
                                               const unsigned short* __restrict__ BT,
                                               const float* __restrict__ bias,
                                               unsigned short* __restrict__ C,
                                               const float* __restrict__ a_s,
                                               const float* __restrict__ a_d,
                                               float* __restrict__ als, float* __restrict__ ald,
                                               int M, int Ncols, int act){
  __shared__ float sred[2][128];
  __shared__ float dred[2][128];
  const int lane = threadIdx.x & 63;
  const int wave = threadIdx.x >> 6;
  const int brow = blockIdx.x * 128;
  const int row0 = brow + (wave >> 1) * 64;
  const int col0 = blockIdx.y * 128 + (wave & 1) * 64;
  const int r15 = lane & 15;
  const int kg = (lane >> 4) * 8;
  f32x4 acc[4][4] = {};
  int ar[4];
#pragma unroll
  for (int m = 0; m < 4; ++m){
    int r = row0 + m * 16 + r15;
    ar[m] = (r < M) ? r : (M - 1);
  }
#pragma unroll
  for (int kt = 0; kt < K; kt += 32){
    bf16x8 a[4], b[4];
#pragma unroll
    for (int m = 0; m < 4; ++m)
      a[m] = *reinterpret_cast<const bf16x8*>(&A[(size_t)ar[m] * K + kt + kg]);
#pragma unroll
    for (int n = 0; n < 4; ++n)
      b[n] = *reinterpret_cast<const bf16x8*>(&BT[(size_t)(col0 + n * 16 + r15) * K + kt + kg]);
#pragma unroll
    for (int m = 0; m < 4; ++m)
#pragma unroll
      for (int n = 0; n < 4; ++n)
        acc[m][n] = __builtin_amdgcn_mfma_f32_16x16x32_bf16(a[m], b[n], acc[m][n], 0, 0, 0);
  }
  // C store (bf16) + optional bias/elu; PERM permutes the stored column
#pragma unroll
  for (int m = 0; m < 4; ++m){
#pragma unroll
    for (int n = 0; n < 4; ++n){
      int c = col0 + n * 16 + r15;
      float bsv = bias ? bias[c] : 0.f;
      int cs = PERM ? pi(c) : c;
#pragma unroll
      for (int q = 0; q < 4; ++q){
        int r = row0 + m * 16 + (lane >> 4) * 4 + q;
        if (r < M){
          float v = acc[m][n][q] + bsv;
          if (act) v = (v > 0.f) ? v : expm1f(v);
          C[(size_t)r * Ncols + cs] = f2b(v);
        }
      }
    }
  }
  // fused attention logits (fp32 accumulators, full head dot within this block)
  if (a_s){
    const int head = blockIdx.y;
    const int cin = (wave & 1) * 64;
    float asv[4], adv[4];
#pragma unroll
    for (int n = 0; n < 4; ++n){
      int c = head * EMB + cin + n * 16 + r15;
      asv[n] = a_s[c]; adv[n] = a_d[c];
    }
#pragma unroll
    for (int m = 0; m < 4; ++m){
#pragma unroll
      for (int q = 0; q < 4; ++q){
        float ps = acc[m][0][q] * asv[0] + acc[m][1][q] * asv[1]
                 + acc[m][2][q] * asv[2] + acc[m][3][q] * asv[3];
        float pd = acc[m][0][q] * adv[0] + acc[m][1][q] * adv[1]
                 + acc[m][2][q] * adv[2] + acc[m][3][q] * adv[3];
#pragma unroll
        for (int off = 1; off < 16; off <<= 1){
          ps += __shfl_xor(ps, off);
          pd += __shfl_xor(pd, off);
        }
        if (r15 == 0){
          int rowl = (wave >> 1) * 64 + m * 16 + (lane >> 4) * 4 + q;
          sred[wave & 1][rowl] = ps;
          dred[wave & 1][rowl] = pd;
        }
      }
    }
    __syncthreads();
    if (threadIdx.x < 128){
      int rowl = threadIdx.x;
      int r = brow + rowl;
      if (r < M){
        als[(size_t)r * 3 + head] = sred[0][rowl] + sred[1][rowl];
        ald[(size_t)r * 3 + head] = dred[0][rowl] + dred[1][rowl];
      }
    }
  }
}

// ---------------- edge-parallel unnormalized attention weights (NO atomics) ----------------
// softmax shift-invariant, |logit| O(1) by construction -> exp w/o max is safe in fp32.
__global__ void k_ex(const float* __restrict__ als, const float* __restrict__ ald,
                     const int* __restrict__ esrc, const int* __restrict__ edst,
                     float4* __restrict__ ex4, int total){
  int i = blockIdx.x * 256 + threadIdx.x;
  if (i >= total) return;
  int s = esrc[i], d = edst[i];
  f32x3 as = *reinterpret_cast<const f32x3*>(&als[s * 3]);
  f32x3 ad = *reinterpret_cast<const f32x3*>(&ald[d * 3]);
  float e0 = __expf(lrelu(as.x + ad.x));
  float e1 = __expf(lrelu(as.y + ad.y));
  float e2 = __expf(lrelu(as.z + ad.z));
  ex4[i] = make_float4(e0, e1, e2, 0.f);
}

// ---------------- GAT aggregation (one wave per dst node) + bias + elu -> bf16 ----
// h in pi layout: lane's 6 channels = bytes [lane*12, lane*12+12) = 3 dwords (head pairs).
__global__ __launch_bounds__(256) void k_agg(const unsigned short* __restrict__ h,
                                             const float4* __restrict__ ex4,
                                             const int* __restrict__ rs, const int* __restrict__ esrc,
                                             const float* __restrict__ bias,
                                             unsigned short* __restrict__ out, int Nn){
  int n = blockIdx.x * 4 + (threadIdx.x >> 6);
  int lane = threadIdx.x & 63;
  if (n >= Nn) return;
  int start = rs[n], end = rs[n + 1];
  // pass A: denominators, lane-parallel contiguous reads
  float d0 = 0.f, d1 = 0.f, d2 = 0.f;
  for (int i = start + lane; i < end; i += 64){
    float4 e = ex4[i];
    d0 += e.x; d1 += e.y; d2 += e.z;
  }
  for (int off = 32; off; off >>= 1){
    d0 += __shfl_xor(d0, off);
    d1 += __shfl_xor(d1, off);
    d2 += __shfl_xor(d2, off);
  }
  float iv[3] = {1.f / (d0 + 1e-16f), 1.f / (d1 + 1e-16f), 1.f / (d2 + 1e-16f)};
  // pass B: serial gather+FMA, unrolled x8
  float acc[6] = {0.f, 0.f, 0.f, 0.f, 0.f, 0.f};
  const int l3 = lane * 3;
  int i = start;
  for (; i + 7 < end; i += 8){
    u32x3 hv[8]; float4 ev[8];
#pragma unroll
    for (int u = 0; u < 8; ++u){
      int s = esrc[i + u];
      hv[u] = *reinterpret_cast<const u32x3*>(reinterpret_cast<const unsigned*>(h + (size_t)s * HE) + l3);
      ev[u] = ex4[i + u];
    }
#pragma unroll
    for (int u = 0; u < 8; ++u){
      acc[0] += ev[u].x * b2f((unsigned short)hv[u].x);
      acc[1] += ev[u].x * b2f((unsigned short)(hv[u].x >> 16));
      acc[2] += ev[u].y * b2f((unsigned short)hv[u].y);
      acc[3] += ev[u].y * b2f((unsigned short)(hv[u].y >> 16));
      acc[4] += ev[u].z * b2f((unsigned short)hv[u].z);
      acc[5] += ev[u].z * b2f((unsigned short)(hv[u].z >> 16));
    }
  }
  for (; i < end; ++i){
    int s = esrc[i];
    u32x3 v = *reinterpret_cast<const u32x3*>(reinterpret_cast<const unsigned*>(h + (size_t)s * HE) + l3);
    float4 e = ex4[i];
    acc[0] += e.x * b2f((unsigned short)v.x);
    acc[1] += e.x * b2f((unsigned short)(v.x >> 16));
    acc[2] += e.y * b2f((unsigned short)v.y);
    acc[3] += e.y * b2f((unsigned short)(v.y >> 16));
    acc[4] += e.z * b2f((unsigned short)v.z);
    acc[5] += e.z * b2f((unsigned short)(v.z >> 16));
  }
  unsigned ov[3];
#pragma unroll
  for (int hh = 0; hh < 3; ++hh){
    int ch = 128 * hh + 2 * lane;           // original channel ids for bias
    float v0 = acc[2 * hh] * iv[hh] + bias[ch];
    float v1 = acc[2 * hh + 1] * iv[hh] + bias[ch + 1];
    v0 = (v0 > 0.f) ? v0 : expm1f(v0);
    v1 = (v1 > 0.f) ? v1 : expm1f(v1);
    ov[hh] = (unsigned)f2b(v0) | ((unsigned)f2b(v1) << 16);
  }
  unsigned* orow = reinterpret_cast<unsigned*>(out + (size_t)n * HE) + l3;
  *reinterpret_cast<u32x3*>(orow) = *reinterpret_cast<u32x3*>(ov);   // pi layout
}

// ---------------- final dot: sigmoid(Z @ Wl2 + bl2), Z bf16 [N,512] ----------------
__global__ __launch_bounds__(256) void k_head(const unsigned short* __restrict__ Z,
                                              const float* __restrict__ w, const float* __restrict__ b,
                                              float* __restrict__ out, int Nn){
  int n = blockIdx.x * 4 + (threadIdx.x >> 6);
  int lane = threadIdx.x & 63;
  if (n >= Nn) return;
  const unsigned short* zr = Z + (size_t)n * 512;
  float sum = 0.f;
#pragma unroll
  for (int j = 0; j < 4; ++j){
    int ch = 128 * j + 2 * lane;
    unsigned v = *reinterpret_cast<const unsigned*>(&zr[ch]);
    sum += b2f((unsigned short)v) * w[ch] + b2f((unsigned short)(v >> 16)) * w[ch + 1];
  }
  for (int off = 32; off; off >>= 1) sum += __shfl_xor(sum, off);
  if (lane == 0) out[n] = 1.f / (1.f + __expf(-(sum + b[0])));
}

extern "C" void kernel_launch(void* const* d_in, const int* in_sizes, int n_in,
                              void* d_out, int out_size, void* d_ws, size_t ws_size,
                              hipStream_t stream){
  const float* x   = (const float*)d_in[0];
  const int*   ei  = (const int*)d_in[1];
  const int N = in_sizes[0] / F_IN;
  const int E = in_sizes[1] / 2;
  const float* W[3]  = {(const float*)d_in[2], (const float*)d_in[6], (const float*)d_in[10]};
  const float* AS[3] = {(const float*)d_in[3], (const float*)d_in[7], (const float*)d_in[11]};
  const float* AD[3] = {(const float*)d_in[4], (const float*)d_in[8], (const float*)d_in[12]};
  const float* BB[3] = {(const float*)d_in[5], (const float*)d_in[9], (const float*)d_in[13]};
  const float* WH[3] = {(const float*)d_in[14], (const float*)d_in[16], (const float*)d_in[18]};
  const float* BH[3] = {(const float*)d_in[15], (const float*)d_in[17], (const float*)d_in[19]};
  const float* Wl1 = (const float*)d_in[20];
  const float* bl1 = (const float*)d_in[21];
  const float* Wl2 = (const float*)d_in[22];
  const float* bl2 = (const float*)d_in[23];
  float* out = (float*)d_out;

  // ---- workspace layout ----
  char* ws = (char*)d_ws;
  size_t off = 0;
  auto alloc = [&](size_t bytes) -> char* {
    char* p = ws + off;
    off = (off + bytes + 255) & ~(size_t)255;
    return p;
  };
  int*   row_start = (int*)alloc((size_t)(N + 1) * 4);
  int*   fill      = (int*)alloc((size_t)N * 4);
  int*   esrc      = (int*)alloc((size_t)(E + N) * 4);
  int*   edst      = (int*)alloc((size_t)(E + N) * 4);
  int*   bsum      = (int*)alloc(256 * 4);
  float* als       = (float*)alloc((size_t)N * 3 * 4);
  float* ald       = (float*)alloc((size_t)N * 3 * 4);
  float4* ex4      = (float4*)alloc((size_t)(E + N) * 16);
  unsigned short* xb = (unsigned short*)alloc((size_t)N * F_IN * 2);   // x bf16
  unsigned short* P  = (unsigned short*)alloc((size_t)N * HE * 2);     // h [N,384] bf16 (pi layout)
  unsigned short* Q  = (unsigned short*)alloc((size_t)N * HE * 2);     // agg out bf16 (pi layout)
  unsigned short* R  = (unsigned short*)alloc((size_t)N * F_IN * 2);   // head-transform out (plain)
  unsigned short* Z  = (unsigned short*)alloc((size_t)N * 512 * 2);    // MLP hidden bf16
  // weight slabs
  unsigned short* W1T  = (unsigned short*)alloc((size_t)F_IN * HE * 2);  // [384,128]
  unsigned short* W2T  = (unsigned short*)alloc((size_t)F_IN * HE * 2);
  unsigned short* W3T  = (unsigned short*)alloc((size_t)F_IN * HE * 2);
  unsigned short* WhPT[3];
  for (int l = 0; l < 3; ++l)
    WhPT[l] = (unsigned short*)alloc((size_t)HE * F_IN * 2);            // [128,384] K pi-permuted
  unsigned short* Wl1T = (unsigned short*)alloc((size_t)F_IN * 512 * 2); // [512,128]

  // ---- CSR by dst (counting sort) ----
  hipMemsetAsync(fill, 0, (size_t)N * 4, stream);
  k_hist<<<2048, 256, 0, stream>>>(ei, E, N, fill);
  int nsb = (N + 255) / 256;
  k_scan1<<<nsb, 256, 0, stream>>>(fill, N, row_start, bsum);
  k_scan2<<<1, 256, 0, stream>>>(bsum, nsb);
  k_scan3<<<nsb, 256, 0, stream>>>(row_start, bsum, N);
  hipMemsetAsync(fill, 0, (size_t)N * 4, stream);
  k_scatter<<<2048, 256, 0, stream>>>(ei, E, N, row_start, fill, esrc, edst);

  // ---- dtype prep ----
  k_f2b4<<<(N * F_IN / 4 + 255) / 256, 256, 0, stream>>>(x, xb, N * F_IN / 4);
  k_w2bt<<<(F_IN * HE + 255) / 256, 256, 0, stream>>>(W[0], W1T, F_IN, HE);
  k_w2bt<<<(F_IN * HE + 255) / 256, 256, 0, stream>>>(W[1], W2T, F_IN, HE);
  k_w2bt<<<(F_IN * HE + 255) / 256, 256, 0, stream>>>(W[2], W3T, F_IN, HE);
  for (int l = 0; l < 3; ++l)
    k_w2btp<<<(HE * F_IN + 255) / 256, 256, 0, stream>>>(WH[l], WhPT[l], F_IN);
  k_w2bt<<<(F_IN * 512 + 255) / 256, 256, 0, stream>>>(Wl1, Wl1T, F_IN, 512);

  const int mb = (N + 127) / 128;
  const int nwave = (N + 3) / 4;
  const int tot = E + N;
  const int exg = (tot + 255) / 256;

  const unsigned short* W_T[3] = {W1T, W2T, W3T};
  const unsigned short* xin = xb;
  for (int l = 0; l < 3; ++l){
    // P = xin @ W  [N,384] bf16 (pi store), fused als/ald
    k_mgemm<128, true><<<dim3(mb, 3), 256, 0, stream>>>(xin, W_T[l], nullptr, P,
        AS[l], AD[l], als, ald, N, HE, 0);
    // edge-parallel attention weights
    k_ex<<<exg, 256, 0, stream>>>(als, ald, esrc, edst, ex4, tot);
    // segment aggregation + bias + elu -> Q (pi layout)
    k_agg<<<nwave, 256, 0, stream>>>(P, ex4, row_start, esrc, BB[l], Q, N);
    // head transform: R = Q @ Wh + bh  [N,128] plain layout (K pi-matched)
    k_mgemm<384, false><<<dim3(mb, 1), 256, 0, stream>>>(Q, WhPT[l], BH[l], R,
        nullptr, nullptr, nullptr, nullptr, N, F_IN, 0);
    xin = R;
  }
  // MLP: Z = elu(R @ Wl1 + bl1)  [N,512] bf16
  k_mgemm<128, false><<<dim3(mb, 4), 256, 0, stream>>>(R, Wl1T, bl1, Z,
      nullptr, nullptr, nullptr, nullptr, N, 512, 1);
  // out = sigmoid(Z @ Wl2 + bl2)
  k_head<<<nwave, 256, 0, stream>>>(Z, Wl2, bl2, out, N);
}

// Round 8
// 727.688 us; speedup vs baseline: 1.9116x; 1.0950x over previous
//
#include <hip/hip_runtime.h>
#include <hip/hip_bf16.h>
#include <cstdint>
#include <cstddef>

// GuidedGNN: 3x GATConv(H=3, EMB=128, concat) + head transforms + MLP head.
// R6 (resubmit; container infra failure): k_agg unroll x4 (R5's x8 killed
// occupancy 75->46%); GEMMs LDS-pipelined (BK=64 double-buffer, global_load_lds
// w16, pre-swizzled source + XOR-swizzled ds_read -> conflict-free).

#define F_IN 128
#define EMB  128
#define NH   3
#define HE   (NH*EMB)   // 384

typedef __attribute__((ext_vector_type(8))) short bf16x8;
typedef __attribute__((ext_vector_type(4))) float f32x4;

__device__ __forceinline__ float lrelu(float x){ return x > 0.f ? x : 0.2f * x; }
__device__ __forceinline__ float b2f(unsigned short u){ return __uint_as_float((unsigned)u << 16); }
__device__ __forceinline__ unsigned short f2b(float f){
  __hip_bfloat16 h = __float2bfloat16(f);
  return *reinterpret_cast<unsigned short*>(&h);
}
// channel permutation: orig c in [0,384) -> (c%128/2)*6 + head*2 + (c&1)
__device__ __forceinline__ int pi(int c){
  int hh = c >> 7, w = c & 127;
  return (w >> 1) * 6 + hh * 2 + (w & 1);
}
__device__ __forceinline__ void gload16(const unsigned short* g, unsigned short* l){
  __builtin_amdgcn_global_load_lds((const __attribute__((address_space(1))) unsigned int*)g,
                                   (__attribute__((address_space(3))) unsigned int*)l, 16, 0, 0);
}

struct u32x3 { unsigned x, y, z; };
struct f32x3 { float x, y, z; };

// ---------------- CSR build ----------------
__global__ void k_hist(const int* __restrict__ ei, int E, int Nn, int* __restrict__ cnt){
  int total = E + Nn;
  for (int i = blockIdx.x * blockDim.x + threadIdx.x; i < total; i += gridDim.x * blockDim.x){
    int d = (i < E) ? ei[E + i] : (i - E);
    atomicAdd(&cnt[d], 1);
  }
}

__global__ void k_scan1(const int* __restrict__ cnt, int n, int* __restrict__ rs, int* __restrict__ bsum){
  __shared__ int s[256];
  int t = threadIdx.x;
  int i = blockIdx.x * 256 + t;
  int v = (i < n) ? cnt[i] : 0;
  s[t] = v; __syncthreads();
  for (int off = 1; off < 256; off <<= 1){
    int x = (t >= off) ? s[t - off] : 0;
    __syncthreads();
    s[t] += x;
    __syncthreads();
  }
  if (i < n) rs[i + 1] = s[t];
  if (t == 255) bsum[blockIdx.x] = s[255];
}

__global__ void k_scan2(int* __restrict__ bsum, int nb){
  __shared__ int s[256];
  int t = threadIdx.x;
  int v = (t < nb) ? bsum[t] : 0;
  s[t] = v; __syncthreads();
  for (int off = 1; off < 256; off <<= 1){
    int x = (t >= off) ? s[t - off] : 0;
    __syncthreads();
    s[t] += x;
    __syncthreads();
  }
  if (t < nb) bsum[t] = (t > 0) ? s[t - 1] : 0;  // exclusive
}

__global__ void k_scan3(int* __restrict__ rs, const int* __restrict__ bsum, int n){
  int i = blockIdx.x * 256 + threadIdx.x;
  if (i < n) rs[i + 1] += bsum[blockIdx.x];
  if (i == 0) rs[0] = 0;
}

__global__ void k_scatter(const int* __restrict__ ei, int E, int Nn, const int* __restrict__ rs,
                          int* __restrict__ fill, int* __restrict__ esrc, int* __restrict__ edst){
  int total = E + Nn;
  for (int i = blockIdx.x * blockDim.x + threadIdx.x; i < total; i += gridDim.x * blockDim.x){
    int s, d;
    if (i < E){ s = ei[i]; d = ei[E + i]; } else { s = i - E; d = s; }
    int pos = rs[d] + atomicAdd(&fill[d], 1);
    esrc[pos] = s;
    edst[pos] = d;
  }
}

// ---------------- dtype prep ----------------
__global__ void k_f2b4(const float* __restrict__ in, unsigned short* __restrict__ out, int n4){
  int i = blockIdx.x * blockDim.x + threadIdx.x;
  if (i >= n4) return;
  float4 v = reinterpret_cast<const float4*>(in)[i];
  unsigned short o[4] = {f2b(v.x), f2b(v.y), f2b(v.z), f2b(v.w)};
  *reinterpret_cast<uint2*>(&out[i * 4]) = *reinterpret_cast<uint2*>(o);
}

// W [K, Ncols] fp32 -> BT [Ncols, K] bf16
__global__ void k_w2bt(const float* __restrict__ W, unsigned short* __restrict__ BT, int K, int Ncols){
  int i = blockIdx.x * 256 + threadIdx.x;
  if (i >= K * Ncols) return;
  int r = i / Ncols, c = i % Ncols;
  BT[(size_t)c * K + r] = f2b(W[i]);
}

// W [384, Ncols] fp32 -> BT [Ncols, 384] bf16 with K-dim pi-permuted
__global__ void k_w2btp(const float* __restrict__ W, unsigned short* __restrict__ BT, int Ncols){
  int i = blockIdx.x * 256 + threadIdx.x;
  if (i >= HE * Ncols) return;
  int r = i / Ncols, c = i % Ncols;
  BT[(size_t)c * HE + pi(r)] = f2b(W[i]);
}

// ---------------- LDS-pipelined MFMA GEMM ----------------
// C[M,Ncols](bf16) = A[M,K](bf16) @ BT[Ncols,K]^T, 128x128 tile, 4 waves,
// BK=64 double-buffered LDS staged via global_load_lds(16B). Source addresses
// pre-swizzled so XOR-swizzled ds_read_b128 is bank-conflict-free.
// PERM: store cols pi-permuted. a_s!=null: fused attention logits.
template<int K, bool PERM>
__global__ __launch_bounds__(256, 2) void k_mgemm(const unsigned short* __restrict__ A,
                                                  const unsigned short* __restrict__ BT,
                                                  const float* __restrict__ bias,
                                                  unsigned short* __restrict__ C,
                                                  const float* __restrict__ a_s,
                                                  const float* __restrict__ a_d,
                                                  float* __restrict__ als, float* __restrict__ ald,
                                                  int M, int Ncols, int act){
  __shared__ unsigned short sA[2][8192];   // [buf][128 rows x 64 k] swizzled
  __shared__ unsigned short sB[2][8192];
  const int lane = threadIdx.x & 63;
  const int wave = threadIdx.x >> 6;
  const int brow = blockIdx.x * 128;
  const int bcol = blockIdx.y * 128;
  const int wr = wave >> 1, wc = wave & 1;
  const int r15 = lane & 15;
  const int kg = (lane >> 4) * 8;
  const int row0 = brow + wr * 64;
  const int col0 = bcol + wc * 64;
  f32x4 acc[4][4] = {};

  // chunk geometry (per 16B chunk c of 1024): r=c>>3, k0=((c^r)&7)*8
  const int cbase = wave * 64 + lane;
  auto stage = [&](int buf, int kt){
#pragma unroll
    for (int j = 0; j < 4; ++j){
      int c = cbase + j * 256;
      int r = c >> 3;
      int k0 = ((c ^ r) & 7) * 8;
      int ldsoff = (wave * 64 + j * 256) * 8;   // wave-uniform; HW adds lane*16B
      int ra = brow + r; if (ra >= M) ra = M - 1;
      gload16(&A[(size_t)ra * K + kt + k0], &sA[buf][ldsoff]);
      gload16(&BT[(size_t)(bcol + r) * K + kt + k0], &sB[buf][ldsoff]);
    }
  };
  auto compute = [&](int buf){
#pragma unroll
    for (int ks = 0; ks < 2; ++ks){
      bf16x8 a[4], b[4];
#pragma unroll
      for (int m = 0; m < 4; ++m){
        int row = wr * 64 + m * 16 + r15;
        int idx = (row * 64 + ks * 32 + kg) ^ ((row & 7) << 3);
        a[m] = *reinterpret_cast<const bf16x8*>(&sA[buf][idx]);
      }
#pragma unroll
      for (int n = 0; n < 4; ++n){
        int row = wc * 64 + n * 16 + r15;
        int idx = (row * 64 + ks * 32 + kg) ^ ((row & 7) << 3);
        b[n] = *reinterpret_cast<const bf16x8*>(&sB[buf][idx]);
      }
#pragma unroll
      for (int m = 0; m < 4; ++m)
#pragma unroll
        for (int n = 0; n < 4; ++n)
          acc[m][n] = __builtin_amdgcn_mfma_f32_16x16x32_bf16(a[m], b[n], acc[m][n], 0, 0, 0);
    }
  };

  constexpr int NK = K / 64;
  stage(0, 0);
  int cur = 0;
#pragma unroll
  for (int t = 0; t < NK; ++t){
    __syncthreads();                       // drains stage(cur); protects prev reads
    if (t + 1 < NK) stage(cur ^ 1, (t + 1) * 64);  // overlaps compute below
    compute(cur);
    cur ^= 1;
  }

  // C store (bf16) + optional bias/elu; PERM permutes the stored column
#pragma unroll
  for (int m = 0; m < 4; ++m){
#pragma unroll
    for (int n = 0; n < 4; ++n){
      int c = col0 + n * 16 + r15;
      float bsv = bias ? bias[c] : 0.f;
      int cs = PERM ? pi(c) : c;
#pragma unroll
      for (int q = 0; q < 4; ++q){
        int r = row0 + m * 16 + (lane >> 4) * 4 + q;
        if (r < M){
          float v = acc[m][n][q] + bsv;
          if (act) v = (v > 0.f) ? v : expm1f(v);
          C[(size_t)r * Ncols + cs] = f2b(v);
        }
      }
    }
  }
  // fused attention logits (fp32 accumulators, full head dot within this block)
  if (a_s){
    __syncthreads();                       // sA reuse as float scratch
    float* sred = reinterpret_cast<float*>(&sA[0][0]);   // [2][128]
    float* dred = sred + 256;
    const int head = blockIdx.y;
    const int cin = wc * 64;
    float asv[4], adv[4];
#pragma unroll
    for (int n = 0; n < 4; ++n){
      int c = head * EMB + cin + n * 16 + r15;
      asv[n] = a_s[c]; adv[n] = a_d[c];
    }
#pragma unroll
    for (int m = 0; m < 4; ++m){
#pragma unroll
      for (int q = 0; q < 4; ++q){
        float ps = acc[m][0][q] * asv[0] + acc[m][1][q] * asv[1]
                 + acc[m][2][q] * asv[2] + acc[m][3][q] * asv[3];
        float pd = acc[m][0][q] * adv[0] + acc[m][1][q] * adv[1]
                 + acc[m][2][q] * adv[2] + acc[m][3][q] * adv[3];
#pragma unroll
        for (int off = 1; off < 16; off <<= 1){
          ps += __shfl_xor(ps, off);
          pd += __shfl_xor(pd, off);
        }
        if (r15 == 0){
          int rowl = wr * 64 + m * 16 + (lane >> 4) * 4 + q;
          sred[wc * 128 + rowl] = ps;
          dred[wc * 128 + rowl] = pd;
        }
      }
    }
    __syncthreads();
    if (threadIdx.x < 128){
      int rowl = threadIdx.x;
      int r = brow + rowl;
      if (r < M){
        als[(size_t)r * 3 + head] = sred[rowl] + sred[128 + rowl];
        ald[(size_t)r * 3 + head] = dred[rowl] + dred[128 + rowl];
      }
    }
  }
}

// ---------------- edge-parallel unnormalized attention weights (NO atomics) ----------------
// softmax shift-invariant, |logit| O(1) by construction -> exp w/o max is safe in fp32.
__global__ void k_ex(const float* __restrict__ als, const float* __restrict__ ald,
                     const int* __restrict__ esrc, const int* __restrict__ edst,
                     float4* __restrict__ ex4, int total){
  int i = blockIdx.x * 256 + threadIdx.x;
  if (i >= total) return;
  int s = esrc[i], d = edst[i];
  f32x3 as = *reinterpret_cast<const f32x3*>(&als[s * 3]);
  f32x3 ad = *reinterpret_cast<const f32x3*>(&ald[d * 3]);
  float e0 = __expf(lrelu(as.x + ad.x));
  float e1 = __expf(lrelu(as.y + ad.y));
  float e2 = __expf(lrelu(as.z + ad.z));
  ex4[i] = make_float4(e0, e1, e2, 0.f);
}

// ---------------- GAT aggregation (one wave per dst node) + bias + elu -> bf16 ----
// h in pi layout: lane's 6 channels = bytes [lane*12, lane*12+12) = 3 dwords (head pairs).
__global__ __launch_bounds__(256) void k_agg(const unsigned short* __restrict__ h,
                                             const float4* __restrict__ ex4,
                                             const int* __restrict__ rs, const int* __restrict__ esrc,
                                             const float* __restrict__ bias,
                                             unsigned short* __restrict__ out, int Nn){
  int n = blockIdx.x * 4 + (threadIdx.x >> 6);
  int lane = threadIdx.x & 63;
  if (n >= Nn) return;
  int start = rs[n], end = rs[n + 1];
  // pass A: denominators, lane-parallel contiguous reads
  float d0 = 0.f, d1 = 0.f, d2 = 0.f;
  for (int i = start + lane; i < end; i += 64){
    float4 e = ex4[i];
    d0 += e.x; d1 += e.y; d2 += e.z;
  }
  for (int off = 32; off; off >>= 1){
    d0 += __shfl_xor(d0, off);
    d1 += __shfl_xor(d1, off);
    d2 += __shfl_xor(d2, off);
  }
  float iv[3] = {1.f / (d0 + 1e-16f), 1.f / (d1 + 1e-16f), 1.f / (d2 + 1e-16f)};
  // pass B: serial gather+FMA, unrolled x4 (x8 cost occupancy in R5)
  float acc[6] = {0.f, 0.f, 0.f, 0.f, 0.f, 0.f};
  const int l3 = lane * 3;
  int i = start;
  for (; i + 3 < end; i += 4){
    u32x3 hv[4]; float4 ev[4];
#pragma unroll
    for (int u = 0; u < 4; ++u){
      int s = esrc[i + u];
      hv[u] = *reinterpret_cast<const u32x3*>(reinterpret_cast<const unsigned*>(h + (size_t)s * HE) + l3);
      ev[u] = ex4[i + u];
    }
#pragma unroll
    for (int u = 0; u < 4; ++u){
      acc[0] += ev[u].x * b2f((unsigned short)hv[u].x);
      acc[1] += ev[u].x * b2f((unsigned short)(hv[u].x >> 16));
      acc[2] += ev[u].y * b2f((unsigned short)hv[u].y);
      acc[3] += ev[u].y * b2f((unsigned short)(hv[u].y >> 16));
      acc[4] += ev[u].z * b2f((unsigned short)hv[u].z);
      acc[5] += ev[u].z * b2f((unsigned short)(hv[u].z >> 16));
    }
  }
  for (; i < end; ++i){
    int s = esrc[i];
    u32x3 v = *reinterpret_cast<const u32x3*>(reinterpret_cast<const unsigned*>(h + (size_t)s * HE) + l3);
    float4 e = ex4[i];
    acc[0] += e.x * b2f((unsigned short)v.x);
    acc[1] += e.x * b2f((unsigned short)(v.x >> 16));
    acc[2] += e.y * b2f((unsigned short)v.y);
    acc[3] += e.y * b2f((unsigned short)(v.y >> 16));
    acc[4] += e.z * b2f((unsigned short)v.z);
    acc[5] += e.z * b2f((unsigned short)(v.z >> 16));
  }
  unsigned ov[3];
#pragma unroll
  for (int hh = 0; hh < 3; ++hh){
    int ch = 128 * hh + 2 * lane;           // original channel ids for bias
    float v0 = acc[2 * hh] * iv[hh] + bias[ch];
    float v1 = acc[2 * hh + 1] * iv[hh] + bias[ch + 1];
    v0 = (v0 > 0.f) ? v0 : expm1f(v0);
    v1 = (v1 > 0.f) ? v1 : expm1f(v1);
    ov[hh] = (unsigned)f2b(v0) | ((unsigned)f2b(v1) << 16);
  }
  unsigned* orow = reinterpret_cast<unsigned*>(out + (size_t)n * HE) + l3;
  *reinterpret_cast<u32x3*>(orow) = *reinterpret_cast<u32x3*>(ov);   // pi layout
}

// ---------------- final dot: sigmoid(Z @ Wl2 + bl2), Z bf16 [N,512] ----------------
__global__ __launch_bounds__(256) void k_head(const unsigned short* __restrict__ Z,
                                              const float* __restrict__ w, const float* __restrict__ b,
                                              float* __restrict__ out, int Nn){
  int n = blockIdx.x * 4 + (threadIdx.x >> 6);
  int lane = threadIdx.x & 63;
  if (n >= Nn) return;
  const unsigned short* zr = Z + (size_t)n * 512;
  float sum = 0.f;
#pragma unroll
  for (int j = 0; j < 4; ++j){
    int ch = 128 * j + 2 * lane;
    unsigned v = *reinterpret_cast<const unsigned*>(&zr[ch]);
    sum += b2f((unsigned short)v) * w[ch] + b2f((unsigned short)(v >> 16)) * w[ch + 1];
  }
  for (int off = 32; off; off >>= 1) sum += __shfl_xor(sum, off);
  if (lane == 0) out[n] = 1.f / (1.f + __expf(-(sum + b[0])));
}

extern "C" void kernel_launch(void* const* d_in, const int* in_sizes, int n_in,
                              void* d_out, int out_size, void* d_ws, size_t ws_size,
                              hipStream_t stream){
  const float* x   = (const float*)d_in[0];
  const int*   ei  = (const int*)d_in[1];
  const int N = in_sizes[0] / F_IN;
  const int E = in_sizes[1] / 2;
  const float* W[3]  = {(const float*)d_in[2], (const float*)d_in[6], (const float*)d_in[10]};
  const float* AS[3] = {(const float*)d_in[3], (const float*)d_in[7], (const float*)d_in[11]};
  const float* AD[3] = {(const float*)d_in[4], (const float*)d_in[8], (const float*)d_in[12]};
  const float* BB[3] = {(const float*)d_in[5], (const float*)d_in[9], (const float*)d_in[13]};
  const float* WH[3] = {(const float*)d_in[14], (const float*)d_in[16], (const float*)d_in[18]};
  const float* BH[3] = {(const float*)d_in[15], (const float*)d_in[17], (const float*)d_in[19]};
  const float* Wl1 = (const float*)d_in[20];
  const float* bl1 = (const float*)d_in[21];
  const float* Wl2 = (const float*)d_in[22];
  const float* bl2 = (const float*)d_in[23];
  float* out = (float*)d_out;

  // ---- workspace layout ----
  char* ws = (char*)d_ws;
  size_t off = 0;
  auto alloc = [&](size_t bytes) -> char* {
    char* p = ws + off;
    off = (off + bytes + 255) & ~(size_t)255;
    return p;
  };
  int*   row_start = (int*)alloc((size_t)(N + 1) * 4);
  int*   fill      = (int*)alloc((size_t)N * 4);
  int*   esrc      = (int*)alloc((size_t)(E + N) * 4);
  int*   edst      = (int*)alloc((size_t)(E + N) * 4);
  int*   bsum      = (int*)alloc(256 * 4);
  float* als       = (float*)alloc((size_t)N * 3 * 4);
  float* ald       = (float*)alloc((size_t)N * 3 * 4);
  float4* ex4      = (float4*)alloc((size_t)(E + N) * 16);
  unsigned short* xb = (unsigned short*)alloc((size_t)N * F_IN * 2);   // x bf16
  unsigned short* P  = (unsigned short*)alloc((size_t)N * HE * 2);     // h [N,384] bf16 (pi layout)
  unsigned short* Q  = (unsigned short*)alloc((size_t)N * HE * 2);     // agg out bf16 (pi layout)
  unsigned short* R  = (unsigned short*)alloc((size_t)N * F_IN * 2);   // head-transform out (plain)
  unsigned short* Z  = (unsigned short*)alloc((size_t)N * 512 * 2);    // MLP hidden bf16
  // weight slabs
  unsigned short* W1T  = (unsigned short*)alloc((size_t)F_IN * HE * 2);  // [384,128]
  unsigned short* W2T  = (unsigned short*)alloc((size_t)F_IN * HE * 2);
  unsigned short* W3T  = (unsigned short*)alloc((size_t)F_IN * HE * 2);
  unsigned short* WhPT[3];
  for (int l = 0; l < 3; ++l)
    WhPT[l] = (unsigned short*)alloc((size_t)HE * F_IN * 2);            // [128,384] K pi-permuted
  unsigned short* Wl1T = (unsigned short*)alloc((size_t)F_IN * 512 * 2); // [512,128]

  // ---- CSR by dst (counting sort) ----
  hipMemsetAsync(fill, 0, (size_t)N * 4, stream);
  k_hist<<<2048, 256, 0, stream>>>(ei, E, N, fill);
  int nsb = (N + 255) / 256;
  k_scan1<<<nsb, 256, 0, stream>>>(fill, N, row_start, bsum);
  k_scan2<<<1, 256, 0, stream>>>(bsum, nsb);
  k_scan3<<<nsb, 256, 0, stream>>>(row_start, bsum, N);
  hipMemsetAsync(fill, 0, (size_t)N * 4, stream);
  k_scatter<<<2048, 256, 0, stream>>>(ei, E, N, row_start, fill, esrc, edst);

  // ---- dtype prep ----
  k_f2b4<<<(N * F_IN / 4 + 255) / 256, 256, 0, stream>>>(x, xb, N * F_IN / 4);
  k_w2bt<<<(F_IN * HE + 255) / 256, 256, 0, stream>>>(W[0], W1T, F_IN, HE);
  k_w2bt<<<(F_IN * HE + 255) / 256, 256, 0, stream>>>(W[1], W2T, F_IN, HE);
  k_w2bt<<<(F_IN * HE + 255) / 256, 256, 0, stream>>>(W[2], W3T, F_IN, HE);
  for (int l = 0; l < 3; ++l)
    k_w2btp<<<(HE * F_IN + 255) / 256, 256, 0, stream>>>(WH[l], WhPT[l], F_IN);
  k_w2bt<<<(F_IN * 512 + 255) / 256, 256, 0, stream>>>(Wl1, Wl1T, F_IN, 512);

  const int mb = (N + 127) / 128;
  const int nwave = (N + 3) / 4;
  const int tot = E + N;
  const int exg = (tot + 255) / 256;

  const unsigned short* W_T[3] = {W1T, W2T, W3T};
  const unsigned short* xin = xb;
  for (int l = 0; l < 3; ++l){
    // P = xin @ W  [N,384] bf16 (pi store), fused als/ald
    k_mgemm<128, true><<<dim3(mb, 3), 256, 0, stream>>>(xin, W_T[l], nullptr, P,
        AS[l], AD[l], als, ald, N, HE, 0);
    // edge-parallel attention weights
    k_ex<<<exg, 256, 0, stream>>>(als, ald, esrc, edst, ex4, tot);
    // segment aggregation + bias + elu -> Q (pi layout)
    k_agg<<<nwave, 256, 0, stream>>>(P, ex4, row_start, esrc, BB[l], Q, N);
    // head transform: R = Q @ Wh + bh  [N,128] plain layout (K pi-matched)
    k_mgemm<384, false><<<dim3(mb, 1), 256, 0, stream>>>(Q, WhPT[l], BH[l], R,
        nullptr, nullptr, nullptr, nullptr, N, F_IN, 0);
    xin = R;
  }
  // MLP: Z = elu(R @ Wl1 + bl1)  [N,512] bf16
  k_mgemm<128, false><<<dim3(mb, 4), 256, 0, stream>>>(R, Wl1T, bl1, Z,
      nullptr, nullptr, nullptr, nullptr, N, 512, 1);
  // out = sigmoid(Z @ Wl2 + bl2)
  k_head<<<nwave, 256, 0, stream>>>(Z, Wl2, bl2, out, N);
}

// Round 9
// 684.875 us; speedup vs baseline: 2.0311x; 1.0625x over previous
//
#include <hip/hip_runtime.h>
#include <hip/hip_bf16.h>
#include <cstdint>
#include <cstddef>

// GuidedGNN: 3x GATConv(H=3, EMB=128, concat) + head transforms + MLP head.
// R7: CSR scatter made atomic-free (rank captured in hist; R4 lesson: scattered
// device atomics ~10x slower than a plain pass); k_ex fused into k_agg pass A
// with per-wave LDS ex-cache (256-edge cap, recompute fallback). GEMMs = R6.

#define F_IN 128
#define EMB  128
#define NH   3
#define HE   (NH*EMB)   // 384
#define EXCAP 256       // per-wave LDS ex-cache entries (max deg ~45 in practice)

typedef __attribute__((ext_vector_type(8))) short bf16x8;
typedef __attribute__((ext_vector_type(4))) float f32x4;

__device__ __forceinline__ float lrelu(float x){ return x > 0.f ? x : 0.2f * x; }
__device__ __forceinline__ float b2f(unsigned short u){ return __uint_as_float((unsigned)u << 16); }
__device__ __forceinline__ unsigned short f2b(float f){
  __hip_bfloat16 h = __float2bfloat16(f);
  return *reinterpret_cast<unsigned short*>(&h);
}
// channel permutation: orig c in [0,384) -> (c%128/2)*6 + head*2 + (c&1)
__device__ __forceinline__ int pi(int c){
  int hh = c >> 7, w = c & 127;
  return (w >> 1) * 6 + hh * 2 + (w & 1);
}
__device__ __forceinline__ void gload16(const unsigned short* g, unsigned short* l){
  __builtin_amdgcn_global_load_lds((const __attribute__((address_space(1))) unsigned int*)g,
                                   (__attribute__((address_space(3))) unsigned int*)l, 16, 0, 0);
}

struct u32x3 { unsigned x, y, z; };
struct f32x3 { float x, y, z; };

// ---------------- CSR build ----------------
// hist: count incoming edges per dst AND capture each edge's rank within its dst.
__global__ void k_hist(const int* __restrict__ ei, int E, int Nn, int* __restrict__ cnt,
                       int* __restrict__ rank){
  int total = E + Nn;
  for (int i = blockIdx.x * blockDim.x + threadIdx.x; i < total; i += gridDim.x * blockDim.x){
    int d = (i < E) ? ei[E + i] : (i - E);
    rank[i] = atomicAdd(&cnt[d], 1);
  }
}

__global__ void k_scan1(const int* __restrict__ cnt, int n, int* __restrict__ rs, int* __restrict__ bsum){
  __shared__ int s[256];
  int t = threadIdx.x;
  int i = blockIdx.x * 256 + t;
  int v = (i < n) ? cnt[i] : 0;
  s[t] = v; __syncthreads();
  for (int off = 1; off < 256; off <<= 1){
    int x = (t >= off) ? s[t - off] : 0;
    __syncthreads();
    s[t] += x;
    __syncthreads();
  }
  if (i < n) rs[i + 1] = s[t];
  if (t == 255) bsum[blockIdx.x] = s[255];
}

__global__ void k_scan2(int* __restrict__ bsum, int nb){
  __shared__ int s[256];
  int t = threadIdx.x;
  int v = (t < nb) ? bsum[t] : 0;
  s[t] = v; __syncthreads();
  for (int off = 1; off < 256; off <<= 1){
    int x = (t >= off) ? s[t - off] : 0;
    __syncthreads();
    s[t] += x;
    __syncthreads();
  }
  if (t < nb) bsum[t] = (t > 0) ? s[t - 1] : 0;  // exclusive
}

__global__ void k_scan3(int* __restrict__ rs, const int* __restrict__ bsum, int n){
  int i = blockIdx.x * 256 + threadIdx.x;
  if (i < n) rs[i + 1] += bsum[blockIdx.x];
  if (i == 0) rs[0] = 0;
}

// scatter: NO atomics (rank precomputed in hist)
__global__ void k_scatter(const int* __restrict__ ei, int E, int Nn, const int* __restrict__ rs,
                          const int* __restrict__ rank, int* __restrict__ esrc){
  int total = E + Nn;
  for (int i = blockIdx.x * blockDim.x + threadIdx.x; i < total; i += gridDim.x * blockDim.x){
    int s, d;
    if (i < E){ s = ei[i]; d = ei[E + i]; } else { s = i - E; d = s; }
    esrc[rs[d] + rank[i]] = s;
  }
}

// ---------------- dtype prep ----------------
__global__ void k_f2b4(const float* __restrict__ in, unsigned short* __restrict__ out, int n4){
  int i = blockIdx.x * blockDim.x + threadIdx.x;
  if (i >= n4) return;
  float4 v = reinterpret_cast<const float4*>(in)[i];
  unsigned short o[4] = {f2b(v.x), f2b(v.y), f2b(v.z), f2b(v.w)};
  *reinterpret_cast<uint2*>(&out[i * 4]) = *reinterpret_cast<uint2*>(o);
}

// W [K, Ncols] fp32 -> BT [Ncols, K] bf16
__global__ void k_w2bt(const float* __restrict__ W, unsigned short* __restrict__ BT, int K, int Ncols){
  int i = blockIdx.x * 256 + threadIdx.x;
  if (i >= K * Ncols) return;
  int r = i / Ncols, c = i % Ncols;
  BT[(size_t)c * K + r] = f2b(W[i]);
}

// W [384, Ncols] fp32 -> BT [Ncols, 384] bf16 with K-dim pi-permuted
__global__ void k_w2btp(const float* __restrict__ W, unsigned short* __restrict__ BT, int Ncols){
  int i = blockIdx.x * 256 + threadIdx.x;
  if (i >= HE * Ncols) return;
  int r = i / Ncols, c = i % Ncols;
  BT[(size_t)c * HE + pi(r)] = f2b(W[i]);
}

// ---------------- LDS-pipelined MFMA GEMM (unchanged from R6) ----------------
template<int K, bool PERM>
__global__ __launch_bounds__(256, 2) void k_mgemm(const unsigned short* __restrict__ A,
                                                  const unsigned short* __restrict__ BT,
                                                  const float* __restrict__ bias,
                                                  unsigned short* __restrict__ C,
                                                  const float* __restrict__ a_s,
                                                  const float* __restrict__ a_d,
                                                  float* __restrict__ als, float* __restrict__ ald,
                                                  int M, int Ncols, int act){
  __shared__ unsigned short sA[2][8192];   // [buf][128 rows x 64 k] swizzled
  __shared__ unsigned short sB[2][8192];
  const int lane = threadIdx.x & 63;
  const int wave = threadIdx.x >> 6;
  const int brow = blockIdx.x * 128;
  const int bcol = blockIdx.y * 128;
  const int wr = wave >> 1, wc = wave & 1;
  const int r15 = lane & 15;
  const int kg = (lane >> 4) * 8;
  const int row0 = brow + wr * 64;
  const int col0 = bcol + wc * 64;
  f32x4 acc[4][4] = {};

  // chunk geometry (per 16B chunk c of 1024): r=c>>3, k0=((c^r)&7)*8
  const int cbase = wave * 64 + lane;
  auto stage = [&](int buf, int kt){
#pragma unroll
    for (int j = 0; j < 4; ++j){
      int c = cbase + j * 256;
      int r = c >> 3;
      int k0 = ((c ^ r) & 7) * 8;
      int ldsoff = (wave * 64 + j * 256) * 8;   // wave-uniform; HW adds lane*16B
      int ra = brow + r; if (ra >= M) ra = M - 1;
      gload16(&A[(size_t)ra * K + kt + k0], &sA[buf][ldsoff]);
      gload16(&BT[(size_t)(bcol + r) * K + kt + k0], &sB[buf][ldsoff]);
    }
  };
  auto compute = [&](int buf){
#pragma unroll
    for (int ks = 0; ks < 2; ++ks){
      bf16x8 a[4], b[4];
#pragma unroll
      for (int m = 0; m < 4; ++m){
        int row = wr * 64 + m * 16 + r15;
        int idx = (row * 64 + ks * 32 + kg) ^ ((row & 7) << 3);
        a[m] = *reinterpret_cast<const bf16x8*>(&sA[buf][idx]);
      }
#pragma unroll
      for (int n = 0; n < 4; ++n){
        int row = wc * 64 + n * 16 + r15;
        int idx = (row * 64 + ks * 32 + kg) ^ ((row & 7) << 3);
        b[n] = *reinterpret_cast<const bf16x8*>(&sB[buf][idx]);
      }
#pragma unroll
      for (int m = 0; m < 4; ++m)
#pragma unroll
        for (int n = 0; n < 4; ++n)
          acc[m][n] = __builtin_amdgcn_mfma_f32_16x16x32_bf16(a[m], b[n], acc[m][n], 0, 0, 0);
    }
  };

  constexpr int NK = K / 64;
  stage(0, 0);
  int cur = 0;
#pragma unroll
  for (int t = 0; t < NK; ++t){
    __syncthreads();                       // drains stage(cur); protects prev reads
    if (t + 1 < NK) stage(cur ^ 1, (t + 1) * 64);  // overlaps compute below
    compute(cur);
    cur ^= 1;
  }

  // C store (bf16) + optional bias/elu; PERM permutes the stored column
#pragma unroll
  for (int m = 0; m < 4; ++m){
#pragma unroll
    for (int n = 0; n < 4; ++n){
      int c = col0 + n * 16 + r15;
      float bsv = bias ? bias[c] : 0.f;
      int cs = PERM ? pi(c) : c;
#pragma unroll
      for (int q = 0; q < 4; ++q){
        int r = row0 + m * 16 + (lane >> 4) * 4 + q;
        if (r < M){
          float v = acc[m][n][q] + bsv;
          if (act) v = (v > 0.f) ? v : expm1f(v);
          C[(size_t)r * Ncols + cs] = f2b(v);
        }
      }
    }
  }
  // fused attention logits (fp32 accumulators, full head dot within this block)
  if (a_s){
    __syncthreads();                       // sA reuse as float scratch
    float* sred = reinterpret_cast<float*>(&sA[0][0]);   // [2][128]
    float* dred = sred + 256;
    const int head = blockIdx.y;
    const int cin = wc * 64;
    float asv[4], adv[4];
#pragma unroll
    for (int n = 0; n < 4; ++n){
      int c = head * EMB + cin + n * 16 + r15;
      asv[n] = a_s[c]; adv[n] = a_d[c];
    }
#pragma unroll
    for (int m = 0; m < 4; ++m){
#pragma unroll
      for (int q = 0; q < 4; ++q){
        float ps = acc[m][0][q] * asv[0] + acc[m][1][q] * asv[1]
                 + acc[m][2][q] * asv[2] + acc[m][3][q] * asv[3];
        float pd = acc[m][0][q] * adv[0] + acc[m][1][q] * adv[1]
                 + acc[m][2][q] * adv[2] + acc[m][3][q] * adv[3];
#pragma unroll
        for (int off = 1; off < 16; off <<= 1){
          ps += __shfl_xor(ps, off);
          pd += __shfl_xor(pd, off);
        }
        if (r15 == 0){
          int rowl = wr * 64 + m * 16 + (lane >> 4) * 4 + q;
          sred[wc * 128 + rowl] = ps;
          dred[wc * 128 + rowl] = pd;
        }
      }
    }
    __syncthreads();
    if (threadIdx.x < 128){
      int rowl = threadIdx.x;
      int r = brow + rowl;
      if (r < M){
        als[(size_t)r * 3 + head] = sred[rowl] + sred[128 + rowl];
        ald[(size_t)r * 3 + head] = dred[rowl] + dred[128 + rowl];
      }
    }
  }
}

// ---------------- GAT aggregation, ex fused (one wave per dst node) ----------------
// pass A: lane-parallel exp(lrelu(als[src]+ald[n])) -> denominators + LDS ex-cache.
// pass B: serial gather of h rows (pi layout: lane's 12B) weighted by cached ex.
// softmax shift-invariance: |logit| O(1) -> exp w/o max subtraction safe in fp32.
__global__ __launch_bounds__(256) void k_agg(const unsigned short* __restrict__ h,
                                             const float* __restrict__ als,
                                             const float* __restrict__ ald,
                                             const int* __restrict__ rs, const int* __restrict__ esrc,
                                             const float* __restrict__ bias,
                                             unsigned short* __restrict__ out, int Nn){
  __shared__ float exs[4][EXCAP * 3];      // 12 KB: per-wave ex cache
  int wave = threadIdx.x >> 6;
  int n = blockIdx.x * 4 + wave;
  int lane = threadIdx.x & 63;
  if (n >= Nn) return;
  int start = rs[n], end = rs[n + 1];
  float ad0 = ald[(size_t)n * 3 + 0];
  float ad1 = ald[(size_t)n * 3 + 1];
  float ad2 = ald[(size_t)n * 3 + 2];
  // pass A: lane-parallel ex + denominators, cache to LDS
  float d0 = 0.f, d1 = 0.f, d2 = 0.f;
  for (int i = start + lane; i < end; i += 64){
    int s = esrc[i];
    f32x3 as = *reinterpret_cast<const f32x3*>(&als[(size_t)s * 3]);
    float e0 = __expf(lrelu(as.x + ad0));
    float e1 = __expf(lrelu(as.y + ad1));
    float e2 = __expf(lrelu(as.z + ad2));
    d0 += e0; d1 += e1; d2 += e2;
    int j = i - start;
    if (j < EXCAP){
      exs[wave][j * 3 + 0] = e0;
      exs[wave][j * 3 + 1] = e1;
      exs[wave][j * 3 + 2] = e2;
    }
  }
  for (int off = 32; off; off >>= 1){
    d0 += __shfl_xor(d0, off);
    d1 += __shfl_xor(d1, off);
    d2 += __shfl_xor(d2, off);
  }
  float iv[3] = {1.f / (d0 + 1e-16f), 1.f / (d1 + 1e-16f), 1.f / (d2 + 1e-16f)};
  // pass B: serial gather+FMA, unrolled x4
  float acc[6] = {0.f, 0.f, 0.f, 0.f, 0.f, 0.f};
  const int l3 = lane * 3;
  const float* exw = exs[wave];
  int i = start;
  int nfast = end;
  if (end - start > EXCAP) nfast = start + EXCAP;   // beyond cache: rare fallback below
  for (; i + 3 < nfast; i += 4){
    u32x3 hv[4]; f32x3 ev[4];
#pragma unroll
    for (int u = 0; u < 4; ++u){
      int s = esrc[i + u];
      hv[u] = *reinterpret_cast<const u32x3*>(reinterpret_cast<const unsigned*>(h + (size_t)s * HE) + l3);
      int j = (i + u - start) * 3;
      ev[u].x = exw[j]; ev[u].y = exw[j + 1]; ev[u].z = exw[j + 2];
    }
#pragma unroll
    for (int u = 0; u < 4; ++u){
      acc[0] += ev[u].x * b2f((unsigned short)hv[u].x);
      acc[1] += ev[u].x * b2f((unsigned short)(hv[u].x >> 16));
      acc[2] += ev[u].y * b2f((unsigned short)hv[u].y);
      acc[3] += ev[u].y * b2f((unsigned short)(hv[u].y >> 16));
      acc[4] += ev[u].z * b2f((unsigned short)hv[u].z);
      acc[5] += ev[u].z * b2f((unsigned short)(hv[u].z >> 16));
    }
  }
  for (; i < end; ++i){
    int j = i - start;
    int s = esrc[i];
    float e0, e1, e2;
    if (j < EXCAP){
      e0 = exw[j * 3]; e1 = exw[j * 3 + 1]; e2 = exw[j * 3 + 2];
    } else {           // recompute (deg > EXCAP; not taken for this graph)
      f32x3 as = *reinterpret_cast<const f32x3*>(&als[(size_t)s * 3]);
      e0 = __expf(lrelu(as.x + ad0));
      e1 = __expf(lrelu(as.y + ad1));
      e2 = __expf(lrelu(as.z + ad2));
    }
    u32x3 v = *reinterpret_cast<const u32x3*>(reinterpret_cast<const unsigned*>(h + (size_t)s * HE) + l3);
    acc[0] += e0 * b2f((unsigned short)v.x);
    acc[1] += e0 * b2f((unsigned short)(v.x >> 16));
    acc[2] += e1 * b2f((unsigned short)v.y);
    acc[3] += e1 * b2f((unsigned short)(v.y >> 16));
    acc[4] += e2 * b2f((unsigned short)v.z);
    acc[5] += e2 * b2f((unsigned short)(v.z >> 16));
  }
  unsigned ov[3];
#pragma unroll
  for (int hh = 0; hh < 3; ++hh){
    int ch = 128 * hh + 2 * lane;           // original channel ids for bias
    float v0 = acc[2 * hh] * iv[hh] + bias[ch];
    float v1 = acc[2 * hh + 1] * iv[hh] + bias[ch + 1];
    v0 = (v0 > 0.f) ? v0 : expm1f(v0);
    v1 = (v1 > 0.f) ? v1 : expm1f(v1);
    ov[hh] = (unsigned)f2b(v0) | ((unsigned)f2b(v1) << 16);
  }
  unsigned* orow = reinterpret_cast<unsigned*>(out + (size_t)n * HE) + l3;
  *reinterpret_cast<u32x3*>(orow) = *reinterpret_cast<u32x3*>(ov);   // pi layout
}

// ---------------- final dot: sigmoid(Z @ Wl2 + bl2), Z bf16 [N,512] ----------------
__global__ __launch_bounds__(256) void k_head(const unsigned short* __restrict__ Z,
                                              const float* __restrict__ w, const float* __restrict__ b,
                                              float* __restrict__ out, int Nn){
  int n = blockIdx.x * 4 + (threadIdx.x >> 6);
  int lane = threadIdx.x & 63;
  if (n >= Nn) return;
  const unsigned short* zr = Z + (size_t)n * 512;
  float sum = 0.f;
#pragma unroll
  for (int j = 0; j < 4; ++j){
    int ch = 128 * j + 2 * lane;
    unsigned v = *reinterpret_cast<const unsigned*>(&zr[ch]);
    sum += b2f((unsigned short)v) * w[ch] + b2f((unsigned short)(v >> 16)) * w[ch + 1];
  }
  for (int off = 32; off; off >>= 1) sum += __shfl_xor(sum, off);
  if (lane == 0) out[n] = 1.f / (1.f + __expf(-(sum + b[0])));
}

extern "C" void kernel_launch(void* const* d_in, const int* in_sizes, int n_in,
                              void* d_out, int out_size, void* d_ws, size_t ws_size,
                              hipStream_t stream){
  const float* x   = (const float*)d_in[0];
  const int*   ei  = (const int*)d_in[1];
  const int N = in_sizes[0] / F_IN;
  const int E = in_sizes[1] / 2;
  const float* W[3]  = {(const float*)d_in[2], (const float*)d_in[6], (const float*)d_in[10]};
  const float* AS[3] = {(const float*)d_in[3], (const float*)d_in[7], (const float*)d_in[11]};
  const float* AD[3] = {(const float*)d_in[4], (const float*)d_in[8], (const float*)d_in[12]};
  const float* BB[3] = {(const float*)d_in[5], (const float*)d_in[9], (const float*)d_in[13]};
  const float* WH[3] = {(const float*)d_in[14], (const float*)d_in[16], (const float*)d_in[18]};
  const float* BH[3] = {(const float*)d_in[15], (const float*)d_in[17], (const float*)d_in[19]};
  const float* Wl1 = (const float*)d_in[20];
  const float* bl1 = (const float*)d_in[21];
  const float* Wl2 = (const float*)d_in[22];
  const float* bl2 = (const float*)d_in[23];
  float* out = (float*)d_out;

  // ---- workspace layout ----
  char* ws = (char*)d_ws;
  size_t off = 0;
  auto alloc = [&](size_t bytes) -> char* {
    char* p = ws + off;
    off = (off + bytes + 255) & ~(size_t)255;
    return p;
  };
  int*   row_start = (int*)alloc((size_t)(N + 1) * 4);
  int*   cnt       = (int*)alloc((size_t)N * 4);
  int*   esrc      = (int*)alloc((size_t)(E + N) * 4);
  int*   rank      = (int*)alloc((size_t)(E + N) * 4);
  int*   bsum      = (int*)alloc(256 * 4);
  float* als       = (float*)alloc((size_t)N * 3 * 4);
  float* ald       = (float*)alloc((size_t)N * 3 * 4);
  unsigned short* xb = (unsigned short*)alloc((size_t)N * F_IN * 2);   // x bf16
  unsigned short* P  = (unsigned short*)alloc((size_t)N * HE * 2);     // h [N,384] bf16 (pi layout)
  unsigned short* Q  = (unsigned short*)alloc((size_t)N * HE * 2);     // agg out bf16 (pi layout)
  unsigned short* R  = (unsigned short*)alloc((size_t)N * F_IN * 2);   // head-transform out (plain)
  unsigned short* Z  = (unsigned short*)alloc((size_t)N * 512 * 2);    // MLP hidden bf16
  // weight slabs
  unsigned short* W1T  = (unsigned short*)alloc((size_t)F_IN * HE * 2);  // [384,128]
  unsigned short* W2T  = (unsigned short*)alloc((size_t)F_IN * HE * 2);
  unsigned short* W3T  = (unsigned short*)alloc((size_t)F_IN * HE * 2);
  unsigned short* WhPT[3];
  for (int l = 0; l < 3; ++l)
    WhPT[l] = (unsigned short*)alloc((size_t)HE * F_IN * 2);            // [128,384] K pi-permuted
  unsigned short* Wl1T = (unsigned short*)alloc((size_t)F_IN * 512 * 2); // [512,128]

  // ---- CSR by dst (counting sort; single atomic pass) ----
  hipMemsetAsync(cnt, 0, (size_t)N * 4, stream);
  k_hist<<<2048, 256, 0, stream>>>(ei, E, N, cnt, rank);
  int nsb = (N + 255) / 256;
  k_scan1<<<nsb, 256, 0, stream>>>(cnt, N, row_start, bsum);
  k_scan2<<<1, 256, 0, stream>>>(bsum, nsb);
  k_scan3<<<nsb, 256, 0, stream>>>(row_start, bsum, N);
  k_scatter<<<2048, 256, 0, stream>>>(ei, E, N, row_start, rank, esrc);

  // ---- dtype prep ----
  k_f2b4<<<(N * F_IN / 4 + 255) / 256, 256, 0, stream>>>(x, xb, N * F_IN / 4);
  k_w2bt<<<(F_IN * HE + 255) / 256, 256, 0, stream>>>(W[0], W1T, F_IN, HE);
  k_w2bt<<<(F_IN * HE + 255) / 256, 256, 0, stream>>>(W[1], W2T, F_IN, HE);
  k_w2bt<<<(F_IN * HE + 255) / 256, 256, 0, stream>>>(W[2], W3T, F_IN, HE);
  for (int l = 0; l < 3; ++l)
    k_w2btp<<<(HE * F_IN + 255) / 256, 256, 0, stream>>>(WH[l], WhPT[l], F_IN);
  k_w2bt<<<(F_IN * 512 + 255) / 256, 256, 0, stream>>>(Wl1, Wl1T, F_IN, 512);

  const int mb = (N + 127) / 128;
  const int nwave = (N + 3) / 4;

  const unsigned short* W_T[3] = {W1T, W2T, W3T};
  const unsigned short* xin = xb;
  for (int l = 0; l < 3; ++l){
    // P = xin @ W  [N,384] bf16 (pi store), fused als/ald
    k_mgemm<128, true><<<dim3(mb, 3), 256, 0, stream>>>(xin, W_T[l], nullptr, P,
        AS[l], AD[l], als, ald, N, HE, 0);
    // segment aggregation (ex fused) + bias + elu -> Q (pi layout)
    k_agg<<<nwave, 256, 0, stream>>>(P, als, ald, row_start, esrc, BB[l], Q, N);
    // head transform: R = Q @ Wh + bh  [N,128] plain layout (K pi-matched)
    k_mgemm<384, false><<<dim3(mb, 1), 256, 0, stream>>>(Q, WhPT[l], BH[l], R,
        nullptr, nullptr, nullptr, nullptr, N, F_IN, 0);
    xin = R;
  }
  // MLP: Z = elu(R @ Wl1 + bl1)  [N,512] bf16
  k_mgemm<128, false><<<dim3(mb, 4), 256, 0, stream>>>(R, Wl1T, bl1, Z,
      nullptr, nullptr, nullptr, nullptr, N, 512, 1);
  // out = sigmoid(Z @ Wl2 + bl2)
  k_head<<<nwave, 256, 0, stream>>>(Z, Wl2, bl2, out, N);
}

// Round 10
// 640.244 us; speedup vs baseline: 2.1727x; 1.0697x over previous
//
#include <hip/hip_runtime.h>
#include <hip/hip_bf16.h>
#include <cstdint>
#include <cstddef>

// GuidedGNN: 3x GATConv(H=3, EMB=128, concat) + head transforms + MLP head.
// R8: fused dependent-GEMM kernel k_fused: T = Q@Wh+bh (K=384, LDS dbuf) kept
// in LDS (bf16, XOR-swizzled), then P/Z = T@Wnext (K=128) per 128-col chunk
// with fused als/ald epilogue (chunk==head). Kills R round trips + 3 dispatches.
// k_agg / CSR / layer-1 GEMM unchanged from R7.

#define F_IN 128
#define EMB  128
#define NH   3
#define HE   (NH*EMB)   // 384
#define EXCAP 256       // per-wave LDS ex-cache entries (max deg ~45 in practice)

typedef __attribute__((ext_vector_type(8))) short bf16x8;
typedef __attribute__((ext_vector_type(4))) float f32x4;

__device__ __forceinline__ float lrelu(float x){ return x > 0.f ? x : 0.2f * x; }
__device__ __forceinline__ float b2f(unsigned short u){ return __uint_as_float((unsigned)u << 16); }
__device__ __forceinline__ unsigned short f2b(float f){
  __hip_bfloat16 h = __float2bfloat16(f);
  return *reinterpret_cast<unsigned short*>(&h);
}
// channel permutation: orig c in [0,384) -> (c%128/2)*6 + head*2 + (c&1)
__device__ __forceinline__ int pi(int c){
  int hh = c >> 7, w = c & 127;
  return (w >> 1) * 6 + hh * 2 + (w & 1);
}
__device__ __forceinline__ void gload16(const unsigned short* g, unsigned short* l){
  __builtin_amdgcn_global_load_lds((const __attribute__((address_space(1))) unsigned int*)g,
                                   (__attribute__((address_space(3))) unsigned int*)l, 16, 0, 0);
}

struct u32x3 { unsigned x, y, z; };
struct f32x3 { float x, y, z; };

// ---------------- CSR build ----------------
__global__ void k_hist(const int* __restrict__ ei, int E, int Nn, int* __restrict__ cnt,
                       int* __restrict__ rank){
  int total = E + Nn;
  for (int i = blockIdx.x * blockDim.x + threadIdx.x; i < total; i += gridDim.x * blockDim.x){
    int d = (i < E) ? ei[E + i] : (i - E);
    rank[i] = atomicAdd(&cnt[d], 1);
  }
}

__global__ void k_scan1(const int* __restrict__ cnt, int n, int* __restrict__ rs, int* __restrict__ bsum){
  __shared__ int s[256];
  int t = threadIdx.x;
  int i = blockIdx.x * 256 + t;
  int v = (i < n) ? cnt[i] : 0;
  s[t] = v; __syncthreads();
  for (int off = 1; off < 256; off <<= 1){
    int x = (t >= off) ? s[t - off] : 0;
    __syncthreads();
    s[t] += x;
    __syncthreads();
  }
  if (i < n) rs[i + 1] = s[t];
  if (t == 255) bsum[blockIdx.x] = s[255];
}

__global__ void k_scan2(int* __restrict__ bsum, int nb){
  __shared__ int s[256];
  int t = threadIdx.x;
  int v = (t < nb) ? bsum[t] : 0;
  s[t] = v; __syncthreads();
  for (int off = 1; off < 256; off <<= 1){
    int x = (t >= off) ? s[t - off] : 0;
    __syncthreads();
    s[t] += x;
    __syncthreads();
  }
  if (t < nb) bsum[t] = (t > 0) ? s[t - 1] : 0;  // exclusive
}

__global__ void k_scan3(int* __restrict__ rs, const int* __restrict__ bsum, int n){
  int i = blockIdx.x * 256 + threadIdx.x;
  if (i < n) rs[i + 1] += bsum[blockIdx.x];
  if (i == 0) rs[0] = 0;
}

__global__ void k_scatter(const int* __restrict__ ei, int E, int Nn, const int* __restrict__ rs,
                          const int* __restrict__ rank, int* __restrict__ esrc){
  int total = E + Nn;
  for (int i = blockIdx.x * blockDim.x + threadIdx.x; i < total; i += gridDim.x * blockDim.x){
    int s, d;
    if (i < E){ s = ei[i]; d = ei[E + i]; } else { s = i - E; d = s; }
    esrc[rs[d] + rank[i]] = s;
  }
}

// ---------------- dtype prep ----------------
__global__ void k_f2b4(const float* __restrict__ in, unsigned short* __restrict__ out, int n4){
  int i = blockIdx.x * blockDim.x + threadIdx.x;
  if (i >= n4) return;
  float4 v = reinterpret_cast<const float4*>(in)[i];
  unsigned short o[4] = {f2b(v.x), f2b(v.y), f2b(v.z), f2b(v.w)};
  *reinterpret_cast<uint2*>(&out[i * 4]) = *reinterpret_cast<uint2*>(o);
}

// W [K, Ncols] fp32 -> BT [Ncols, K] bf16
__global__ void k_w2bt(const float* __restrict__ W, unsigned short* __restrict__ BT, int K, int Ncols){
  int i = blockIdx.x * 256 + threadIdx.x;
  if (i >= K * Ncols) return;
  int r = i / Ncols, c = i % Ncols;
  BT[(size_t)c * K + r] = f2b(W[i]);
}

// W [384, Ncols] fp32 -> BT [Ncols, 384] bf16 with K-dim pi-permuted
__global__ void k_w2btp(const float* __restrict__ W, unsigned short* __restrict__ BT, int Ncols){
  int i = blockIdx.x * 256 + threadIdx.x;
  if (i >= HE * Ncols) return;
  int r = i / Ncols, c = i % Ncols;
  BT[(size_t)c * HE + pi(r)] = f2b(W[i]);
}

// ---------------- LDS-pipelined MFMA GEMM (layer-1 only) ----------------
template<int K, bool PERM>
__global__ __launch_bounds__(256, 2) void k_mgemm(const unsigned short* __restrict__ A,
                                                  const unsigned short* __restrict__ BT,
                                                  const float* __restrict__ bias,
                                                  unsigned short* __restrict__ C,
                                                  const float* __restrict__ a_s,
                                                  const float* __restrict__ a_d,
                                                  float* __restrict__ als, float* __restrict__ ald,
                                                  int M, int Ncols, int act){
  __shared__ unsigned short sA[2][8192];   // [buf][128 rows x 64 k] swizzled
  __shared__ unsigned short sB[2][8192];
  const int lane = threadIdx.x & 63;
  const int wave = threadIdx.x >> 6;
  const int brow = blockIdx.x * 128;
  const int bcol = blockIdx.y * 128;
  const int wr = wave >> 1, wc = wave & 1;
  const int r15 = lane & 15;
  const int kg = (lane >> 4) * 8;
  const int row0 = brow + wr * 64;
  const int col0 = bcol + wc * 64;
  f32x4 acc[4][4] = {};

  const int cbase = wave * 64 + lane;
  auto stage = [&](int buf, int kt){
#pragma unroll
    for (int j = 0; j < 4; ++j){
      int c = cbase + j * 256;
      int r = c >> 3;
      int k0 = ((c ^ r) & 7) * 8;
      int ldsoff = (wave * 64 + j * 256) * 8;   // wave-uniform; HW adds lane*16B
      int ra = brow + r; if (ra >= M) ra = M - 1;
      gload16(&A[(size_t)ra * K + kt + k0], &sA[buf][ldsoff]);
      gload16(&BT[(size_t)(bcol + r) * K + kt + k0], &sB[buf][ldsoff]);
    }
  };
  auto compute = [&](int buf){
#pragma unroll
    for (int ks = 0; ks < 2; ++ks){
      bf16x8 a[4], b[4];
#pragma unroll
      for (int m = 0; m < 4; ++m){
        int row = wr * 64 + m * 16 + r15;
        int idx = (row * 64 + ks * 32 + kg) ^ ((row & 7) << 3);
        a[m] = *reinterpret_cast<const bf16x8*>(&sA[buf][idx]);
      }
#pragma unroll
      for (int n = 0; n < 4; ++n){
        int row = wc * 64 + n * 16 + r15;
        int idx = (row * 64 + ks * 32 + kg) ^ ((row & 7) << 3);
        b[n] = *reinterpret_cast<const bf16x8*>(&sB[buf][idx]);
      }
#pragma unroll
      for (int m = 0; m < 4; ++m)
#pragma unroll
        for (int n = 0; n < 4; ++n)
          acc[m][n] = __builtin_amdgcn_mfma_f32_16x16x32_bf16(a[m], b[n], acc[m][n], 0, 0, 0);
    }
  };

  constexpr int NK = K / 64;
  stage(0, 0);
  int cur = 0;
#pragma unroll
  for (int t = 0; t < NK; ++t){
    __syncthreads();
    if (t + 1 < NK) stage(cur ^ 1, (t + 1) * 64);
    compute(cur);
    cur ^= 1;
  }

#pragma unroll
  for (int m = 0; m < 4; ++m){
#pragma unroll
    for (int n = 0; n < 4; ++n){
      int c = col0 + n * 16 + r15;
      float bsv = bias ? bias[c] : 0.f;
      int cs = PERM ? pi(c) : c;
#pragma unroll
      for (int q = 0; q < 4; ++q){
        int r = row0 + m * 16 + (lane >> 4) * 4 + q;
        if (r < M){
          float v = acc[m][n][q] + bsv;
          if (act) v = (v > 0.f) ? v : expm1f(v);
          C[(size_t)r * Ncols + cs] = f2b(v);
        }
      }
    }
  }
  if (a_s){
    __syncthreads();
    float* sred = reinterpret_cast<float*>(&sA[0][0]);   // [2][128]
    float* dred = sred + 256;
    const int head = blockIdx.y;
    const int cin = wc * 64;
    float asv[4], adv[4];
#pragma unroll
    for (int n = 0; n < 4; ++n){
      int c = head * EMB + cin + n * 16 + r15;
      asv[n] = a_s[c]; adv[n] = a_d[c];
    }
#pragma unroll
    for (int m = 0; m < 4; ++m){
#pragma unroll
      for (int q = 0; q < 4; ++q){
        float ps = acc[m][0][q] * asv[0] + acc[m][1][q] * asv[1]
                 + acc[m][2][q] * asv[2] + acc[m][3][q] * asv[3];
        float pd = acc[m][0][q] * adv[0] + acc[m][1][q] * adv[1]
                 + acc[m][2][q] * adv[2] + acc[m][3][q] * adv[3];
#pragma unroll
        for (int off = 1; off < 16; off <<= 1){
          ps += __shfl_xor(ps, off);
          pd += __shfl_xor(pd, off);
        }
        if (r15 == 0){
          int rowl = wr * 64 + m * 16 + (lane >> 4) * 4 + q;
          sred[wc * 128 + rowl] = ps;
          dred[wc * 128 + rowl] = pd;
        }
      }
    }
    __syncthreads();
    if (threadIdx.x < 128){
      int rowl = threadIdx.x;
      int r = brow + rowl;
      if (r < M){
        als[(size_t)r * 3 + head] = sred[rowl] + sred[128 + rowl];
        ald[(size_t)r * 3 + head] = dred[rowl] + dred[128 + rowl];
      }
    }
  }
}

// ---------------- fused dependent GEMM: T = A@B1^T + bias1 (K=384, LDS),
// then C_chunk = T@B2_chunk^T (+bias2)(+elu) for NCH 128-col chunks.
// NCH==3: pi store + als/ald epilogue (chunk==head). NCH==4: Z path (512 cols).
template<int NCH>
__global__ __launch_bounds__(256, 2) void k_fused(const unsigned short* __restrict__ A,
                                                  const unsigned short* __restrict__ B1,
                                                  const float* __restrict__ bias1,
                                                  const unsigned short* __restrict__ B2,
                                                  const float* __restrict__ bias2,
                                                  unsigned short* __restrict__ C,
                                                  const float* __restrict__ a_s,
                                                  const float* __restrict__ a_d,
                                                  float* __restrict__ als, float* __restrict__ ald,
                                                  int M, int act2){
  __shared__ unsigned short sA[2][8192];   // stage-1 A dbuf; then T[128][128] swizzled
  __shared__ unsigned short sB[2][8192];   // stage-1 B dbuf; then B2 chunk (32KB)
  __shared__ float sred[2][128];
  __shared__ float dred[2][128];
  const int lane = threadIdx.x & 63;
  const int wave = threadIdx.x >> 6;
  const int brow = blockIdx.x * 128;
  const int wr = wave >> 1, wc = wave & 1;
  const int r15 = lane & 15;
  const int kg = (lane >> 4) * 8;
  const int qrow = (lane >> 4) * 4;
  f32x4 acc[4][4] = {};
  const int cbase = wave * 64 + lane;

  // ---- stage 1: T = A(pi)@B1^T, K=384, BK=64 double-buffered ----
  auto stage1 = [&](int buf, int kt){
#pragma unroll
    for (int j = 0; j < 4; ++j){
      int c = cbase + j * 256;
      int r = c >> 3;
      int k0 = ((c ^ r) & 7) * 8;
      int ldsoff = (wave * 64 + j * 256) * 8;   // wave-uniform; HW adds lane*16B
      int ra = brow + r; if (ra >= M) ra = M - 1;
      gload16(&A[(size_t)ra * HE + kt + k0], &sA[buf][ldsoff]);
      gload16(&B1[(size_t)r * HE + kt + k0], &sB[buf][ldsoff]);
    }
  };
  stage1(0, 0);
  int cur = 0;
#pragma unroll
  for (int t = 0; t < 6; ++t){
    __syncthreads();
    if (t + 1 < 6) stage1(cur ^ 1, (t + 1) * 64);
#pragma unroll
    for (int ks = 0; ks < 2; ++ks){
      bf16x8 a[4], b[4];
#pragma unroll
      for (int m = 0; m < 4; ++m){
        int row = wr * 64 + m * 16 + r15;
        int idx = (row * 64 + ks * 32 + kg) ^ ((row & 7) << 3);
        a[m] = *reinterpret_cast<const bf16x8*>(&sA[cur][idx]);
      }
#pragma unroll
      for (int n = 0; n < 4; ++n){
        int row = wc * 64 + n * 16 + r15;
        int idx = (row * 64 + ks * 32 + kg) ^ ((row & 7) << 3);
        b[n] = *reinterpret_cast<const bf16x8*>(&sB[cur][idx]);
      }
#pragma unroll
      for (int m = 0; m < 4; ++m)
#pragma unroll
        for (int n = 0; n < 4; ++n)
          acc[m][n] = __builtin_amdgcn_mfma_f32_16x16x32_bf16(a[m], b[n], acc[m][n], 0, 0, 0);
    }
    cur ^= 1;
  }
  __syncthreads();   // all stage-1 LDS reads done
  // write T = acc + bias1 (bf16) into sA region, stride 128, XOR swizzle
  unsigned short* T = &sA[0][0];
#pragma unroll
  for (int m = 0; m < 4; ++m){
#pragma unroll
    for (int n = 0; n < 4; ++n){
      int col = wc * 64 + n * 16 + r15;
      float bv = bias1[col];
#pragma unroll
      for (int q = 0; q < 4; ++q){
        int row = wr * 64 + m * 16 + qrow + q;
        T[(row * 128 + col) ^ ((row & 7) << 3)] = f2b(acc[m][n][q] + bv);
      }
    }
  }
  __syncthreads();   // T visible to all

  // ---- stage 2: per 128-col chunk, C = T@B2_chunk^T ----
  unsigned short* Bs = &sB[0][0];
#pragma unroll
  for (int cc = 0; cc < NCH; ++cc){
    if (cc > 0) __syncthreads();   // prev chunk's Bs reads done
#pragma unroll
    for (int j = 0; j < 8; ++j){
      int c = cbase + j * 256;     // 0..2047 (128 rows x 16 chunks, CPR=16)
      int r = c >> 4;
      int cr = c & 15;
      int k0 = ((cr & 8) | ((cr ^ r) & 7)) * 8;
      int ldsoff = (wave * 64 + j * 256) * 8;
      gload16(&B2[(size_t)(cc * 128 + r) * 128 + k0], &Bs[ldsoff]);
    }
    __syncthreads();               // staged chunk visible
#pragma unroll
    for (int m = 0; m < 4; ++m)
#pragma unroll
      for (int n = 0; n < 4; ++n)
        acc[m][n] = (f32x4){0.f, 0.f, 0.f, 0.f};
#pragma unroll
    for (int ks = 0; ks < 4; ++ks){
      bf16x8 a[4], b[4];
#pragma unroll
      for (int m = 0; m < 4; ++m){
        int row = wr * 64 + m * 16 + r15;
        int idx = (row * 128 + ks * 32 + kg) ^ ((row & 7) << 3);
        a[m] = *reinterpret_cast<const bf16x8*>(&T[idx]);
      }
#pragma unroll
      for (int n = 0; n < 4; ++n){
        int row = wc * 64 + n * 16 + r15;
        int idx = (row * 128 + ks * 32 + kg) ^ ((row & 7) << 3);
        b[n] = *reinterpret_cast<const bf16x8*>(&Bs[idx]);
      }
#pragma unroll
      for (int m = 0; m < 4; ++m)
#pragma unroll
        for (int n = 0; n < 4; ++n)
          acc[m][n] = __builtin_amdgcn_mfma_f32_16x16x32_bf16(a[m], b[n], acc[m][n], 0, 0, 0);
    }
    // store chunk
#pragma unroll
    for (int m = 0; m < 4; ++m){
#pragma unroll
      for (int n = 0; n < 4; ++n){
        int cglob = cc * 128 + wc * 64 + n * 16 + r15;
        float bv = bias2 ? bias2[cglob] : 0.f;
        int cs = (NCH == 3) ? pi(cglob) : cglob;
        const int ncols = (NCH == 3) ? HE : 512;
#pragma unroll
        for (int q = 0; q < 4; ++q){
          int rg = brow + wr * 64 + m * 16 + qrow + q;
          if (rg < M){
            float v = acc[m][n][q] + bv;
            if (act2) v = (v > 0.f) ? v : expm1f(v);
            C[(size_t)rg * ncols + cs] = f2b(v);
          }
        }
      }
    }
    // fused attention logits for head = cc
    if (a_s){
      const int cin = wc * 64;
      float asv[4], adv[4];
#pragma unroll
      for (int n = 0; n < 4; ++n){
        int cglob = cc * 128 + cin + n * 16 + r15;
        asv[n] = a_s[cglob]; adv[n] = a_d[cglob];
      }
#pragma unroll
      for (int m = 0; m < 4; ++m){
#pragma unroll
        for (int q = 0; q < 4; ++q){
          float ps = acc[m][0][q] * asv[0] + acc[m][1][q] * asv[1]
                   + acc[m][2][q] * asv[2] + acc[m][3][q] * asv[3];
          float pd = acc[m][0][q] * adv[0] + acc[m][1][q] * adv[1]
                   + acc[m][2][q] * adv[2] + acc[m][3][q] * adv[3];
#pragma unroll
          for (int off = 1; off < 16; off <<= 1){
            ps += __shfl_xor(ps, off);
            pd += __shfl_xor(pd, off);
          }
          if (r15 == 0){
            int rowl = wr * 64 + m * 16 + qrow + q;
            sred[wc][rowl] = ps;
            dred[wc][rowl] = pd;
          }
        }
      }
      __syncthreads();
      if (threadIdx.x < 128){
        int rowl = threadIdx.x;
        int rg = brow + rowl;
        if (rg < M){
          als[(size_t)rg * 3 + cc] = sred[0][rowl] + sred[1][rowl];
          ald[(size_t)rg * 3 + cc] = dred[0][rowl] + dred[1][rowl];
        }
      }
    }
  }
}

// ---------------- GAT aggregation, ex fused (one wave per dst node) ----------------
__global__ __launch_bounds__(256) void k_agg(const unsigned short* __restrict__ h,
                                             const float* __restrict__ als,
                                             const float* __restrict__ ald,
                                             const int* __restrict__ rs, const int* __restrict__ esrc,
                                             const float* __restrict__ bias,
                                             unsigned short* __restrict__ out, int Nn){
  __shared__ float exs[4][EXCAP * 3];      // 12 KB: per-wave ex cache
  int wave = threadIdx.x >> 6;
  int n = blockIdx.x * 4 + wave;
  int lane = threadIdx.x & 63;
  if (n >= Nn) return;
  int start = rs[n], end = rs[n + 1];
  float ad0 = ald[(size_t)n * 3 + 0];
  float ad1 = ald[(size_t)n * 3 + 1];
  float ad2 = ald[(size_t)n * 3 + 2];
  float d0 = 0.f, d1 = 0.f, d2 = 0.f;
  for (int i = start + lane; i < end; i += 64){
    int s = esrc[i];
    f32x3 as = *reinterpret_cast<const f32x3*>(&als[(size_t)s * 3]);
    float e0 = __expf(lrelu(as.x + ad0));
    float e1 = __expf(lrelu(as.y + ad1));
    float e2 = __expf(lrelu(as.z + ad2));
    d0 += e0; d1 += e1; d2 += e2;
    int j = i - start;
    if (j < EXCAP){
      exs[wave][j * 3 + 0] = e0;
      exs[wave][j * 3 + 1] = e1;
      exs[wave][j * 3 + 2] = e2;
    }
  }
  for (int off = 32; off; off >>= 1){
    d0 += __shfl_xor(d0, off);
    d1 += __shfl_xor(d1, off);
    d2 += __shfl_xor(d2, off);
  }
  float iv[3] = {1.f / (d0 + 1e-16f), 1.f / (d1 + 1e-16f), 1.f / (d2 + 1e-16f)};
  float acc[6] = {0.f, 0.f, 0.f, 0.f, 0.f, 0.f};
  const int l3 = lane * 3;
  const float* exw = exs[wave];
  int i = start;
  int nfast = end;
  if (end - start > EXCAP) nfast = start + EXCAP;
  for (; i + 3 < nfast; i += 4){
    u32x3 hv[4]; f32x3 ev[4];
#pragma unroll
    for (int u = 0; u < 4; ++u){
      int s = esrc[i + u];
      hv[u] = *reinterpret_cast<const u32x3*>(reinterpret_cast<const unsigned*>(h + (size_t)s * HE) + l3);
      int j = (i + u - start) * 3;
      ev[u].x = exw[j]; ev[u].y = exw[j + 1]; ev[u].z = exw[j + 2];
    }
#pragma unroll
    for (int u = 0; u < 4; ++u){
      acc[0] += ev[u].x * b2f((unsigned short)hv[u].x);
      acc[1] += ev[u].x * b2f((unsigned short)(hv[u].x >> 16));
      acc[2] += ev[u].y * b2f((unsigned short)hv[u].y);
      acc[3] += ev[u].y * b2f((unsigned short)(hv[u].y >> 16));
      acc[4] += ev[u].z * b2f((unsigned short)hv[u].z);
      acc[5] += ev[u].z * b2f((unsigned short)(hv[u].z >> 16));
    }
  }
  for (; i < end; ++i){
    int j = i - start;
    int s = esrc[i];
    float e0, e1, e2;
    if (j < EXCAP){
      e0 = exw[j * 3]; e1 = exw[j * 3 + 1]; e2 = exw[j * 3 + 2];
    } else {
      f32x3 as = *reinterpret_cast<const f32x3*>(&als[(size_t)s * 3]);
      e0 = __expf(lrelu(as.x + ad0));
      e1 = __expf(lrelu(as.y + ad1));
      e2 = __expf(lrelu(as.z + ad2));
    }
    u32x3 v = *reinterpret_cast<const u32x3*>(reinterpret_cast<const unsigned*>(h + (size_t)s * HE) + l3);
    acc[0] += e0 * b2f((unsigned short)v.x);
    acc[1] += e0 * b2f((unsigned short)(v.x >> 16));
    acc[2] += e1 * b2f((unsigned short)v.y);
    acc[3] += e1 * b2f((unsigned short)(v.y >> 16));
    acc[4] += e2 * b2f((unsigned short)v.z);
    acc[5] += e2 * b2f((unsigned short)(v.z >> 16));
  }
  unsigned ov[3];
#pragma unroll
  for (int hh = 0; hh < 3; ++hh){
    int ch = 128 * hh + 2 * lane;
    float v0 = acc[2 * hh] * iv[hh] + bias[ch];
    float v1 = acc[2 * hh + 1] * iv[hh] + bias[ch + 1];
    v0 = (v0 > 0.f) ? v0 : expm1f(v0);
    v1 = (v1 > 0.f) ? v1 : expm1f(v1);
    ov[hh] = (unsigned)f2b(v0) | ((unsigned)f2b(v1) << 16);
  }
  unsigned* orow = reinterpret_cast<unsigned*>(out + (size_t)n * HE) + l3;
  *reinterpret_cast<u32x3*>(orow) = *reinterpret_cast<u32x3*>(ov);
}

// ---------------- final dot: sigmoid(Z @ Wl2 + bl2), Z bf16 [N,512] ----------------
__global__ __launch_bounds__(256) void k_head(const unsigned short* __restrict__ Z,
                                              const float* __restrict__ w, const float* __restrict__ b,
                                              float* __restrict__ out, int Nn){
  int n = blockIdx.x * 4 + (threadIdx.x >> 6);
  int lane = threadIdx.x & 63;
  if (n >= Nn) return;
  const unsigned short* zr = Z + (size_t)n * 512;
  float sum = 0.f;
#pragma unroll
  for (int j = 0; j < 4; ++j){
    int ch = 128 * j + 2 * lane;
    unsigned v = *reinterpret_cast<const unsigned*>(&zr[ch]);
    sum += b2f((unsigned short)v) * w[ch] + b2f((unsigned short)(v >> 16)) * w[ch + 1];
  }
  for (int off = 32; off; off >>= 1) sum += __shfl_xor(sum, off);
  if (lane == 0) out[n] = 1.f / (1.f + __expf(-(sum + b[0])));
}

extern "C" void kernel_launch(void* const* d_in, const int* in_sizes, int n_in,
                              void* d_out, int out_size, void* d_ws, size_t ws_size,
                              hipStream_t stream){
  const float* x   = (const float*)d_in[0];
  const int*   ei  = (const int*)d_in[1];
  const int N = in_sizes[0] / F_IN;
  const int E = in_sizes[1] / 2;
  const float* W[3]  = {(const float*)d_in[2], (const float*)d_in[6], (const float*)d_in[10]};
  const float* AS[3] = {(const float*)d_in[3], (const float*)d_in[7], (const float*)d_in[11]};
  const float* AD[3] = {(const float*)d_in[4], (const float*)d_in[8], (const float*)d_in[12]};
  const float* BB[3] = {(const float*)d_in[5], (const float*)d_in[9], (const float*)d_in[13]};
  const float* WH[3] = {(const float*)d_in[14], (const float*)d_in[16], (const float*)d_in[18]};
  const float* BH[3] = {(const float*)d_in[15], (const float*)d_in[17], (const float*)d_in[19]};
  const float* Wl1 = (const float*)d_in[20];
  const float* bl1 = (const float*)d_in[21];
  const float* Wl2 = (const float*)d_in[22];
  const float* bl2 = (const float*)d_in[23];
  float* out = (float*)d_out;

  // ---- workspace layout ----
  char* ws = (char*)d_ws;
  size_t off = 0;
  auto alloc = [&](size_t bytes) -> char* {
    char* p = ws + off;
    off = (off + bytes + 255) & ~(size_t)255;
    return p;
  };
  int*   row_start = (int*)alloc((size_t)(N + 1) * 4);
  int*   cnt       = (int*)alloc((size_t)N * 4);
  int*   esrc      = (int*)alloc((size_t)(E + N) * 4);
  int*   rank      = (int*)alloc((size_t)(E + N) * 4);
  int*   bsum      = (int*)alloc(256 * 4);
  float* als       = (float*)alloc((size_t)N * 3 * 4);
  float* ald       = (float*)alloc((size_t)N * 3 * 4);
  unsigned short* xb = (unsigned short*)alloc((size_t)N * F_IN * 2);   // x bf16
  unsigned short* P  = (unsigned short*)alloc((size_t)N * HE * 2);     // h [N,384] bf16 (pi layout)
  unsigned short* Q  = (unsigned short*)alloc((size_t)N * HE * 2);     // agg out bf16 (pi layout)
  unsigned short* Z  = (unsigned short*)alloc((size_t)N * 512 * 2);    // MLP hidden bf16
  // weight slabs
  unsigned short* W1T  = (unsigned short*)alloc((size_t)F_IN * HE * 2);  // [384,128]
  unsigned short* W2T  = (unsigned short*)alloc((size_t)F_IN * HE * 2);
  unsigned short* W3T  = (unsigned short*)alloc((size_t)F_IN * HE * 2);
  unsigned short* WhPT[3];
  for (int l = 0; l < 3; ++l)
    WhPT[l] = (unsigned short*)alloc((size_t)HE * F_IN * 2);            // [128,384] K pi-permuted
  unsigned short* Wl1T = (unsigned short*)alloc((size_t)F_IN * 512 * 2); // [512,128]

  // ---- CSR by dst (counting sort; single atomic pass) ----
  hipMemsetAsync(cnt, 0, (size_t)N * 4, stream);
  k_hist<<<2048, 256, 0, stream>>>(ei, E, N, cnt, rank);
  int nsb = (N + 255) / 256;
  k_scan1<<<nsb, 256, 0, stream>>>(cnt, N, row_start, bsum);
  k_scan2<<<1, 256, 0, stream>>>(bsum, nsb);
  k_scan3<<<nsb, 256, 0, stream>>>(row_start, bsum, N);
  k_scatter<<<2048, 256, 0, stream>>>(ei, E, N, row_start, rank, esrc);

  // ---- dtype prep ----
  k_f2b4<<<(N * F_IN / 4 + 255) / 256, 256, 0, stream>>>(x, xb, N * F_IN / 4);
  k_w2bt<<<(F_IN * HE + 255) / 256, 256, 0, stream>>>(W[0], W1T, F_IN, HE);
  k_w2bt<<<(F_IN * HE + 255) / 256, 256, 0, stream>>>(W[1], W2T, F_IN, HE);
  k_w2bt<<<(F_IN * HE + 255) / 256, 256, 0, stream>>>(W[2], W3T, F_IN, HE);
  for (int l = 0; l < 3; ++l)
    k_w2btp<<<(HE * F_IN + 255) / 256, 256, 0, stream>>>(WH[l], WhPT[l], F_IN);
  k_w2bt<<<(F_IN * 512 + 255) / 256, 256, 0, stream>>>(Wl1, Wl1T, F_IN, 512);

  const int mb = (N + 127) / 128;
  const int nwave = (N + 3) / 4;

  // ---- layer 1: P = x@W1 (pi store) + als/ald; agg ----
  k_mgemm<128, true><<<dim3(mb, 3), 256, 0, stream>>>(xb, W1T, nullptr, P,
      AS[0], AD[0], als, ald, N, HE, 0);
  k_agg<<<nwave, 256, 0, stream>>>(P, als, ald, row_start, esrc, BB[0], Q, N);
  // ---- layer 2: fused (R1 = Q@Wh1+bh1) -> P = R1@W2 (pi) + als/ald; agg ----
  k_fused<3><<<mb, 256, 0, stream>>>(Q, WhPT[0], BH[0], W2T, nullptr, P,
      AS[1], AD[1], als, ald, N, 0);
  k_agg<<<nwave, 256, 0, stream>>>(P, als, ald, row_start, esrc, BB[1], Q, N);
  // ---- layer 3 ----
  k_fused<3><<<mb, 256, 0, stream>>>(Q, WhPT[1], BH[1], W3T, nullptr, P,
      AS[2], AD[2], als, ald, N, 0);
  k_agg<<<nwave, 256, 0, stream>>>(P, als, ald, row_start, esrc, BB[2], Q, N);
  // ---- MLP: fused (R3 = Q@Wh3+bh3) -> Z = elu(R3@Wl1 + bl1) ----
  k_fused<4><<<mb, 256, 0, stream>>>(Q, WhPT[2], BH[2], Wl1T, bl1, Z,
      nullptr, nullptr, nullptr, nullptr, N, 1);
  // out = sigmoid(Z @ Wl2 + bl2)
  k_head<<<nwave, 256, 0, stream>>>(Z, Wl2, bl2, out, N);
}

// Round 11
// 627.312 us; speedup vs baseline: 2.2174x; 1.0206x over previous
//
#include <hip/hip_runtime.h>
#include <hip/hip_bf16.h>
#include <cstdint>
#include <cstddef>

// GuidedGNN: 3x GATConv(H=3, EMB=128, concat) + head transforms + MLP head.
// R9: k_agg split 2 waves/node (halve the serial gather chain; combine partial
// denom + acc via LDS) -- k_agg was latency-bound (HBM 44%, VALU 48%, occ 66%).
// k_fused<4> gains FINAL path: per-chunk dot with Wl2 + sigmoid -> Z never
// materialized, k_head dispatch gone.

#define F_IN 128
#define EMB  128
#define NH   3
#define HE   (NH*EMB)   // 384
#define EXC2 128        // per-wave LDS ex-cache entries (half-degree cap)

typedef __attribute__((ext_vector_type(8))) short bf16x8;
typedef __attribute__((ext_vector_type(4))) float f32x4;

__device__ __forceinline__ float lrelu(float x){ return x > 0.f ? x : 0.2f * x; }
__device__ __forceinline__ float b2f(unsigned short u){ return __uint_as_float((unsigned)u << 16); }
__device__ __forceinline__ unsigned short f2b(float f){
  __hip_bfloat16 h = __float2bfloat16(f);
  return *reinterpret_cast<unsigned short*>(&h);
}
// channel permutation: orig c in [0,384) -> (c%128/2)*6 + head*2 + (c&1)
__device__ __forceinline__ int pi(int c){
  int hh = c >> 7, w = c & 127;
  return (w >> 1) * 6 + hh * 2 + (w & 1);
}
__device__ __forceinline__ void gload16(const unsigned short* g, unsigned short* l){
  __builtin_amdgcn_global_load_lds((const __attribute__((address_space(1))) unsigned int*)g,
                                   (__attribute__((address_space(3))) unsigned int*)l, 16, 0, 0);
}

struct u32x3 { unsigned x, y, z; };
struct f32x3 { float x, y, z; };

// ---------------- CSR build ----------------
__global__ void k_hist(const int* __restrict__ ei, int E, int Nn, int* __restrict__ cnt,
                       int* __restrict__ rank){
  int total = E + Nn;
  for (int i = blockIdx.x * blockDim.x + threadIdx.x; i < total; i += gridDim.x * blockDim.x){
    int d = (i < E) ? ei[E + i] : (i - E);
    rank[i] = atomicAdd(&cnt[d], 1);
  }
}

__global__ void k_scan1(const int* __restrict__ cnt, int n, int* __restrict__ rs, int* __restrict__ bsum){
  __shared__ int s[256];
  int t = threadIdx.x;
  int i = blockIdx.x * 256 + t;
  int v = (i < n) ? cnt[i] : 0;
  s[t] = v; __syncthreads();
  for (int off = 1; off < 256; off <<= 1){
    int x = (t >= off) ? s[t - off] : 0;
    __syncthreads();
    s[t] += x;
    __syncthreads();
  }
  if (i < n) rs[i + 1] = s[t];
  if (t == 255) bsum[blockIdx.x] = s[255];
}

__global__ void k_scan2(int* __restrict__ bsum, int nb){
  __shared__ int s[256];
  int t = threadIdx.x;
  int v = (t < nb) ? bsum[t] : 0;
  s[t] = v; __syncthreads();
  for (int off = 1; off < 256; off <<= 1){
    int x = (t >= off) ? s[t - off] : 0;
    __syncthreads();
    s[t] += x;
    __syncthreads();
  }
  if (t < nb) bsum[t] = (t > 0) ? s[t - 1] : 0;  // exclusive
}

__global__ void k_scan3(int* __restrict__ rs, const int* __restrict__ bsum, int n){
  int i = blockIdx.x * 256 + threadIdx.x;
  if (i < n) rs[i + 1] += bsum[blockIdx.x];
  if (i == 0) rs[0] = 0;
}

__global__ void k_scatter(const int* __restrict__ ei, int E, int Nn, const int* __restrict__ rs,
                          const int* __restrict__ rank, int* __restrict__ esrc){
  int total = E + Nn;
  for (int i = blockIdx.x * blockDim.x + threadIdx.x; i < total; i += gridDim.x * blockDim.x){
    int s, d;
    if (i < E){ s = ei[i]; d = ei[E + i]; } else { s = i - E; d = s; }
    esrc[rs[d] + rank[i]] = s;
  }
}

// ---------------- dtype prep ----------------
__global__ void k_f2b4(const float* __restrict__ in, unsigned short* __restrict__ out, int n4){
  int i = blockIdx.x * blockDim.x + threadIdx.x;
  if (i >= n4) return;
  float4 v = reinterpret_cast<const float4*>(in)[i];
  unsigned short o[4] = {f2b(v.x), f2b(v.y), f2b(v.z), f2b(v.w)};
  *reinterpret_cast<uint2*>(&out[i * 4]) = *reinterpret_cast<uint2*>(o);
}

// W [K, Ncols] fp32 -> BT [Ncols, K] bf16
__global__ void k_w2bt(const float* __restrict__ W, unsigned short* __restrict__ BT, int K, int Ncols){
  int i = blockIdx.x * 256 + threadIdx.x;
  if (i >= K * Ncols) return;
  int r = i / Ncols, c = i % Ncols;
  BT[(size_t)c * K + r] = f2b(W[i]);
}

// W [384, Ncols] fp32 -> BT [Ncols, 384] bf16 with K-dim pi-permuted
__global__ void k_w2btp(const float* __restrict__ W, unsigned short* __restrict__ BT, int Ncols){
  int i = blockIdx.x * 256 + threadIdx.x;
  if (i >= HE * Ncols) return;
  int r = i / Ncols, c = i % Ncols;
  BT[(size_t)c * HE + pi(r)] = f2b(W[i]);
}

// ---------------- LDS-pipelined MFMA GEMM (layer-1 only) ----------------
template<int K, bool PERM>
__global__ __launch_bounds__(256, 2) void k_mgemm(const unsigned short* __restrict__ A,
                                                  const unsigned short* __restrict__ BT,
                                                  const float* __restrict__ bias,
                                                  unsigned short* __restrict__ C,
                                                  const float* __restrict__ a_s,
                                                  const float* __restrict__ a_d,
                                                  float* __restrict__ als, float* __restrict__ ald,
                                                  int M, int Ncols, int act){
  __shared__ unsigned short sA[2][8192];   // [buf][128 rows x 64 k] swizzled
  __shared__ unsigned short sB[2][8192];
  const int lane = threadIdx.x & 63;
  const int wave = threadIdx.x >> 6;
  const int brow = blockIdx.x * 128;
  const int bcol = blockIdx.y * 128;
  const int wr = wave >> 1, wc = wave & 1;
  const int r15 = lane & 15;
  const int kg = (lane >> 4) * 8;
  const int row0 = brow + wr * 64;
  const int col0 = bcol + wc * 64;
  f32x4 acc[4][4] = {};

  const int cbase = wave * 64 + lane;
  auto stage = [&](int buf, int kt){
#pragma unroll
    for (int j = 0; j < 4; ++j){
      int c = cbase + j * 256;
      int r = c >> 3;
      int k0 = ((c ^ r) & 7) * 8;
      int ldsoff = (wave * 64 + j * 256) * 8;   // wave-uniform; HW adds lane*16B
      int ra = brow + r; if (ra >= M) ra = M - 1;
      gload16(&A[(size_t)ra * K + kt + k0], &sA[buf][ldsoff]);
      gload16(&BT[(size_t)(bcol + r) * K + kt + k0], &sB[buf][ldsoff]);
    }
  };
  auto compute = [&](int buf){
#pragma unroll
    for (int ks = 0; ks < 2; ++ks){
      bf16x8 a[4], b[4];
#pragma unroll
      for (int m = 0; m < 4; ++m){
        int row = wr * 64 + m * 16 + r15;
        int idx = (row * 64 + ks * 32 + kg) ^ ((row & 7) << 3);
        a[m] = *reinterpret_cast<const bf16x8*>(&sA[buf][idx]);
      }
#pragma unroll
      for (int n = 0; n < 4; ++n){
        int row = wc * 64 + n * 16 + r15;
        int idx = (row * 64 + ks * 32 + kg) ^ ((row & 7) << 3);
        b[n] = *reinterpret_cast<const bf16x8*>(&sB[buf][idx]);
      }
#pragma unroll
      for (int m = 0; m < 4; ++m)
#pragma unroll
        for (int n = 0; n < 4; ++n)
          acc[m][n] = __builtin_amdgcn_mfma_f32_16x16x32_bf16(a[m], b[n], acc[m][n], 0, 0, 0);
    }
  };

  constexpr int NK = K / 64;
  stage(0, 0);
  int cur = 0;
#pragma unroll
  for (int t = 0; t < NK; ++t){
    __syncthreads();
    if (t + 1 < NK) stage(cur ^ 1, (t + 1) * 64);
    compute(cur);
    cur ^= 1;
  }

#pragma unroll
  for (int m = 0; m < 4; ++m){
#pragma unroll
    for (int n = 0; n < 4; ++n){
      int c = col0 + n * 16 + r15;
      float bsv = bias ? bias[c] : 0.f;
      int cs = PERM ? pi(c) : c;
#pragma unroll
      for (int q = 0; q < 4; ++q){
        int r = row0 + m * 16 + (lane >> 4) * 4 + q;
        if (r < M){
          float v = acc[m][n][q] + bsv;
          if (act) v = (v > 0.f) ? v : expm1f(v);
          C[(size_t)r * Ncols + cs] = f2b(v);
        }
      }
    }
  }
  if (a_s){
    __syncthreads();
    float* sred = reinterpret_cast<float*>(&sA[0][0]);   // [2][128]
    float* dred = sred + 256;
    const int head = blockIdx.y;
    const int cin = wc * 64;
    float asv[4], adv[4];
#pragma unroll
    for (int n = 0; n < 4; ++n){
      int c = head * EMB + cin + n * 16 + r15;
      asv[n] = a_s[c]; adv[n] = a_d[c];
    }
#pragma unroll
    for (int m = 0; m < 4; ++m){
#pragma unroll
      for (int q = 0; q < 4; ++q){
        float ps = acc[m][0][q] * asv[0] + acc[m][1][q] * asv[1]
                 + acc[m][2][q] * asv[2] + acc[m][3][q] * asv[3];
        float pd = acc[m][0][q] * adv[0] + acc[m][1][q] * adv[1]
                 + acc[m][2][q] * adv[2] + acc[m][3][q] * adv[3];
#pragma unroll
        for (int off = 1; off < 16; off <<= 1){
          ps += __shfl_xor(ps, off);
          pd += __shfl_xor(pd, off);
        }
        if (r15 == 0){
          int rowl = wr * 64 + m * 16 + (lane >> 4) * 4 + q;
          sred[wc * 128 + rowl] = ps;
          dred[wc * 128 + rowl] = pd;
        }
      }
    }
    __syncthreads();
    if (threadIdx.x < 128){
      int rowl = threadIdx.x;
      int r = brow + rowl;
      if (r < M){
        als[(size_t)r * 3 + head] = sred[rowl] + sred[128 + rowl];
        ald[(size_t)r * 3 + head] = dred[rowl] + dred[128 + rowl];
      }
    }
  }
}

// ---------------- fused dependent GEMM ----------------
// T = A@B1^T + bias1 (K=384, LDS dbuf) kept in LDS; then per 128-col chunk
// C_chunk = T@B2_chunk^T (+bias2)(+elu). NCH==3: pi store + als/ald epilogue.
// FINAL: no C store; per-chunk dot with w2 accumulated in LDS -> sigmoid out.
template<int NCH, bool FINAL>
__global__ __launch_bounds__(256, 2) void k_fused(const unsigned short* __restrict__ A,
                                                  const unsigned short* __restrict__ B1,
                                                  const float* __restrict__ bias1,
                                                  const unsigned short* __restrict__ B2,
                                                  const float* __restrict__ bias2,
                                                  unsigned short* __restrict__ C,
                                                  const float* __restrict__ a_s,
                                                  const float* __restrict__ a_d,
                                                  float* __restrict__ als, float* __restrict__ ald,
                                                  const float* __restrict__ w2,
                                                  const float* __restrict__ b2s,
                                                  float* __restrict__ outp,
                                                  int M, int act2){
  __shared__ unsigned short sA[2][8192];   // stage-1 A dbuf; then T[128][128] swizzled
  __shared__ unsigned short sB[2][8192];   // stage-1 B dbuf; then B2 chunk (32KB)
  __shared__ float sred[2][128];
  __shared__ float dred[2][128];
  __shared__ float zsum[2][128];
  const int lane = threadIdx.x & 63;
  const int wave = threadIdx.x >> 6;
  const int brow = blockIdx.x * 128;
  const int wr = wave >> 1, wc = wave & 1;
  const int r15 = lane & 15;
  const int kg = (lane >> 4) * 8;
  const int qrow = (lane >> 4) * 4;
  f32x4 acc[4][4] = {};
  const int cbase = wave * 64 + lane;

  if (FINAL && threadIdx.x < 128){ zsum[0][threadIdx.x] = 0.f; zsum[1][threadIdx.x] = 0.f; }

  // ---- stage 1: T = A(pi)@B1^T, K=384, BK=64 double-buffered ----
  auto stage1 = [&](int buf, int kt){
#pragma unroll
    for (int j = 0; j < 4; ++j){
      int c = cbase + j * 256;
      int r = c >> 3;
      int k0 = ((c ^ r) & 7) * 8;
      int ldsoff = (wave * 64 + j * 256) * 8;
      int ra = brow + r; if (ra >= M) ra = M - 1;
      gload16(&A[(size_t)ra * HE + kt + k0], &sA[buf][ldsoff]);
      gload16(&B1[(size_t)r * HE + kt + k0], &sB[buf][ldsoff]);
    }
  };
  stage1(0, 0);
  int cur = 0;
#pragma unroll
  for (int t = 0; t < 6; ++t){
    __syncthreads();
    if (t + 1 < 6) stage1(cur ^ 1, (t + 1) * 64);
#pragma unroll
    for (int ks = 0; ks < 2; ++ks){
      bf16x8 a[4], b[4];
#pragma unroll
      for (int m = 0; m < 4; ++m){
        int row = wr * 64 + m * 16 + r15;
        int idx = (row * 64 + ks * 32 + kg) ^ ((row & 7) << 3);
        a[m] = *reinterpret_cast<const bf16x8*>(&sA[cur][idx]);
      }
#pragma unroll
      for (int n = 0; n < 4; ++n){
        int row = wc * 64 + n * 16 + r15;
        int idx = (row * 64 + ks * 32 + kg) ^ ((row & 7) << 3);
        b[n] = *reinterpret_cast<const bf16x8*>(&sB[cur][idx]);
      }
#pragma unroll
      for (int m = 0; m < 4; ++m)
#pragma unroll
        for (int n = 0; n < 4; ++n)
          acc[m][n] = __builtin_amdgcn_mfma_f32_16x16x32_bf16(a[m], b[n], acc[m][n], 0, 0, 0);
    }
    cur ^= 1;
  }
  __syncthreads();   // all stage-1 LDS reads done
  unsigned short* T = &sA[0][0];
#pragma unroll
  for (int m = 0; m < 4; ++m){
#pragma unroll
    for (int n = 0; n < 4; ++n){
      int col = wc * 64 + n * 16 + r15;
      float bv = bias1[col];
#pragma unroll
      for (int q = 0; q < 4; ++q){
        int row = wr * 64 + m * 16 + qrow + q;
        T[(row * 128 + col) ^ ((row & 7) << 3)] = f2b(acc[m][n][q] + bv);
      }
    }
  }
  __syncthreads();   // T visible

  // ---- stage 2: per 128-col chunk ----
  unsigned short* Bs = &sB[0][0];
#pragma unroll
  for (int cc = 0; cc < NCH; ++cc){
    if (cc > 0) __syncthreads();
#pragma unroll
    for (int j = 0; j < 8; ++j){
      int c = cbase + j * 256;     // 128 rows x 16 chunks (CPR=16)
      int r = c >> 4;
      int cr = c & 15;
      int k0 = ((cr & 8) | ((cr ^ r) & 7)) * 8;
      int ldsoff = (wave * 64 + j * 256) * 8;
      gload16(&B2[(size_t)(cc * 128 + r) * 128 + k0], &Bs[ldsoff]);
    }
    __syncthreads();
#pragma unroll
    for (int m = 0; m < 4; ++m)
#pragma unroll
      for (int n = 0; n < 4; ++n)
        acc[m][n] = (f32x4){0.f, 0.f, 0.f, 0.f};
#pragma unroll
    for (int ks = 0; ks < 4; ++ks){
      bf16x8 a[4], b[4];
#pragma unroll
      for (int m = 0; m < 4; ++m){
        int row = wr * 64 + m * 16 + r15;
        int idx = (row * 128 + ks * 32 + kg) ^ ((row & 7) << 3);
        a[m] = *reinterpret_cast<const bf16x8*>(&T[idx]);
      }
#pragma unroll
      for (int n = 0; n < 4; ++n){
        int row = wc * 64 + n * 16 + r15;
        int idx = (row * 128 + ks * 32 + kg) ^ ((row & 7) << 3);
        b[n] = *reinterpret_cast<const bf16x8*>(&Bs[idx]);
      }
#pragma unroll
      for (int m = 0; m < 4; ++m)
#pragma unroll
        for (int n = 0; n < 4; ++n)
          acc[m][n] = __builtin_amdgcn_mfma_f32_16x16x32_bf16(a[m], b[n], acc[m][n], 0, 0, 0);
    }
    if (FINAL){
      // Z chunk: elu then dot with w2 chunk, accumulate per-row in LDS
      float w2v[4];
#pragma unroll
      for (int n = 0; n < 4; ++n)
        w2v[n] = w2[cc * 128 + wc * 64 + n * 16 + r15];
#pragma unroll
      for (int m = 0; m < 4; ++m){
#pragma unroll
        for (int q = 0; q < 4; ++q){
          float p = 0.f;
#pragma unroll
          for (int n = 0; n < 4; ++n){
            float v = acc[m][n][q] + bias2[cc * 128 + wc * 64 + n * 16 + r15];
            v = (v > 0.f) ? v : expm1f(v);
            p += v * w2v[n];
          }
#pragma unroll
          for (int off = 1; off < 16; off <<= 1) p += __shfl_xor(p, off);
          if (r15 == 0) zsum[wc][wr * 64 + m * 16 + qrow + q] += p;
        }
      }
    } else {
#pragma unroll
      for (int m = 0; m < 4; ++m){
#pragma unroll
        for (int n = 0; n < 4; ++n){
          int cglob = cc * 128 + wc * 64 + n * 16 + r15;
          float bv = bias2 ? bias2[cglob] : 0.f;
          int cs = (NCH == 3) ? pi(cglob) : cglob;
          const int ncols = (NCH == 3) ? HE : 512;
#pragma unroll
          for (int q = 0; q < 4; ++q){
            int rg = brow + wr * 64 + m * 16 + qrow + q;
            if (rg < M){
              float v = acc[m][n][q] + bv;
              if (act2) v = (v > 0.f) ? v : expm1f(v);
              C[(size_t)rg * ncols + cs] = f2b(v);
            }
          }
        }
      }
    }
    // fused attention logits for head = cc
    if (a_s){
      const int cin = wc * 64;
      float asv[4], adv[4];
#pragma unroll
      for (int n = 0; n < 4; ++n){
        int cglob = cc * 128 + cin + n * 16 + r15;
        asv[n] = a_s[cglob]; adv[n] = a_d[cglob];
      }
#pragma unroll
      for (int m = 0; m < 4; ++m){
#pragma unroll
        for (int q = 0; q < 4; ++q){
          float ps = acc[m][0][q] * asv[0] + acc[m][1][q] * asv[1]
                   + acc[m][2][q] * asv[2] + acc[m][3][q] * asv[3];
          float pd = acc[m][0][q] * adv[0] + acc[m][1][q] * adv[1]
                   + acc[m][2][q] * adv[2] + acc[m][3][q] * adv[3];
#pragma unroll
          for (int off = 1; off < 16; off <<= 1){
            ps += __shfl_xor(ps, off);
            pd += __shfl_xor(pd, off);
          }
          if (r15 == 0){
            int rowl = wr * 64 + m * 16 + qrow + q;
            sred[wc][rowl] = ps;
            dred[wc][rowl] = pd;
          }
        }
      }
      __syncthreads();
      if (threadIdx.x < 128){
        int rowl = threadIdx.x;
        int rg = brow + rowl;
        if (rg < M){
          als[(size_t)rg * 3 + cc] = sred[0][rowl] + sred[1][rowl];
          ald[(size_t)rg * 3 + cc] = dred[0][rowl] + dred[1][rowl];
        }
      }
    }
  }
  if (FINAL){
    __syncthreads();
    if (threadIdx.x < 128){
      int rg = brow + threadIdx.x;
      if (rg < M){
        float z = zsum[0][threadIdx.x] + zsum[1][threadIdx.x] + b2s[0];
        outp[rg] = 1.f / (1.f + __expf(-z));
      }
    }
  }
}

// ---------------- GAT aggregation: 2 waves per node ----------------
// Each wave handles half the node's edge range (pass A: ex+denominator with
// LDS ex-cache; pass B: serial gather of h rows). Partials combined via LDS.
__global__ __launch_bounds__(256) void k_agg(const unsigned short* __restrict__ h,
                                             const float* __restrict__ als,
                                             const float* __restrict__ ald,
                                             const int* __restrict__ rs, const int* __restrict__ esrc,
                                             const float* __restrict__ bias,
                                             unsigned short* __restrict__ out, int Nn){
  __shared__ float exs[4][EXC2 * 3];       // 6 KB
  __shared__ float dsum[4][3];
  __shared__ float accx[2][64 * 6];        // 3 KB: sub1 -> sub0 partial acc
  const int wave = threadIdx.x >> 6;
  const int lane = threadIdx.x & 63;
  const int nb = wave >> 1;                // node slot in block
  const int sub = wave & 1;
  const int n = blockIdx.x * 2 + nb;
  const bool valid = (n < Nn);
  int start = 0, end = 0;
  float ad0 = 0.f, ad1 = 0.f, ad2 = 0.f;
  if (valid){
    start = rs[n]; end = rs[n + 1];
    ad0 = ald[(size_t)n * 3 + 0];
    ad1 = ald[(size_t)n * 3 + 1];
    ad2 = ald[(size_t)n * 3 + 2];
  }
  const int mid = (start + end + 1) >> 1;
  const int wsrt = sub ? mid : start;
  const int wend = sub ? end : mid;
  // pass A: ex + partial denominators (lane-parallel over this wave's half)
  float d0 = 0.f, d1 = 0.f, d2 = 0.f;
  for (int i = wsrt + lane; i < wend; i += 64){
    int s = esrc[i];
    f32x3 as = *reinterpret_cast<const f32x3*>(&als[(size_t)s * 3]);
    float e0 = __expf(lrelu(as.x + ad0));
    float e1 = __expf(lrelu(as.y + ad1));
    float e2 = __expf(lrelu(as.z + ad2));
    d0 += e0; d1 += e1; d2 += e2;
    int j = i - wsrt;
    if (j < EXC2){
      exs[wave][j * 3 + 0] = e0;
      exs[wave][j * 3 + 1] = e1;
      exs[wave][j * 3 + 2] = e2;
    }
  }
  for (int off = 32; off; off >>= 1){
    d0 += __shfl_xor(d0, off);
    d1 += __shfl_xor(d1, off);
    d2 += __shfl_xor(d2, off);
  }
  if (lane == 0){ dsum[wave][0] = d0; dsum[wave][1] = d1; dsum[wave][2] = d2; }
  __syncthreads();
  float iv[3];
#pragma unroll
  for (int hh = 0; hh < 3; ++hh)
    iv[hh] = 1.f / (dsum[nb * 2][hh] + dsum[nb * 2 + 1][hh] + 1e-16f);
  // pass B: serial gather+FMA over this wave's half, unrolled x4
  float acc[6] = {0.f, 0.f, 0.f, 0.f, 0.f, 0.f};
  const int l3 = lane * 3;
  const float* exw = exs[wave];
  int i = wsrt;
  int nfast = wend;
  if (wend - wsrt > EXC2) nfast = wsrt + EXC2;
  for (; i + 3 < nfast; i += 4){
    u32x3 hv[4]; f32x3 ev[4];
#pragma unroll
    for (int u = 0; u < 4; ++u){
      int s = esrc[i + u];
      hv[u] = *reinterpret_cast<const u32x3*>(reinterpret_cast<const unsigned*>(h + (size_t)s * HE) + l3);
      int j = (i + u - wsrt) * 3;
      ev[u].x = exw[j]; ev[u].y = exw[j + 1]; ev[u].z = exw[j + 2];
    }
#pragma unroll
    for (int u = 0; u < 4; ++u){
      acc[0] += ev[u].x * b2f((unsigned short)hv[u].x);
      acc[1] += ev[u].x * b2f((unsigned short)(hv[u].x >> 16));
      acc[2] += ev[u].y * b2f((unsigned short)hv[u].y);
      acc[3] += ev[u].y * b2f((unsigned short)(hv[u].y >> 16));
      acc[4] += ev[u].z * b2f((unsigned short)hv[u].z);
      acc[5] += ev[u].z * b2f((unsigned short)(hv[u].z >> 16));
    }
  }
  for (; i < wend; ++i){
    int j = i - wsrt;
    int s = esrc[i];
    float e0, e1, e2;
    if (j < EXC2){
      e0 = exw[j * 3]; e1 = exw[j * 3 + 1]; e2 = exw[j * 3 + 2];
    } else {
      f32x3 as = *reinterpret_cast<const f32x3*>(&als[(size_t)s * 3]);
      e0 = __expf(lrelu(as.x + ad0));
      e1 = __expf(lrelu(as.y + ad1));
      e2 = __expf(lrelu(as.z + ad2));
    }
    u32x3 v = *reinterpret_cast<const u32x3*>(reinterpret_cast<const unsigned*>(h + (size_t)s * HE) + l3);
    acc[0] += e0 * b2f((unsigned short)v.x);
    acc[1] += e0 * b2f((unsigned short)(v.x >> 16));
    acc[2] += e1 * b2f((unsigned short)v.y);
    acc[3] += e1 * b2f((unsigned short)(v.y >> 16));
    acc[4] += e2 * b2f((unsigned short)v.z);
    acc[5] += e2 * b2f((unsigned short)(v.z >> 16));
  }
  // combine halves: sub1 -> LDS, sub0 adds + stores
  if (sub){
#pragma unroll
    for (int k = 0; k < 6; ++k) accx[nb][lane * 6 + k] = acc[k];
  }
  __syncthreads();
  if (!sub && valid){
#pragma unroll
    for (int k = 0; k < 6; ++k) acc[k] += accx[nb][lane * 6 + k];
    unsigned ov[3];
#pragma unroll
    for (int hh = 0; hh < 3; ++hh){
      int ch = 128 * hh + 2 * lane;
      float v0 = acc[2 * hh] * iv[hh] + bias[ch];
      float v1 = acc[2 * hh + 1] * iv[hh] + bias[ch + 1];
      v0 = (v0 > 0.f) ? v0 : expm1f(v0);
      v1 = (v1 > 0.f) ? v1 : expm1f(v1);
      ov[hh] = (unsigned)f2b(v0) | ((unsigned)f2b(v1) << 16);
    }
    unsigned* orow = reinterpret_cast<unsigned*>(out + (size_t)n * HE) + l3;
    *reinterpret_cast<u32x3*>(orow) = *reinterpret_cast<u32x3*>(ov);
  }
}

extern "C" void kernel_launch(void* const* d_in, const int* in_sizes, int n_in,
                              void* d_out, int out_size, void* d_ws, size_t ws_size,
                              hipStream_t stream){
  const float* x   = (const float*)d_in[0];
  const int*   ei  = (const int*)d_in[1];
  const int N = in_sizes[0] / F_IN;
  const int E = in_sizes[1] / 2;
  const float* W[3]  = {(const float*)d_in[2], (const float*)d_in[6], (const float*)d_in[10]};
  const float* AS[3] = {(const float*)d_in[3], (const float*)d_in[7], (const float*)d_in[11]};
  const float* AD[3] = {(const float*)d_in[4], (const float*)d_in[8], (const float*)d_in[12]};
  const float* BB[3] = {(const float*)d_in[5], (const float*)d_in[9], (const float*)d_in[13]};
  const float* WH[3] = {(const float*)d_in[14], (const float*)d_in[16], (const float*)d_in[18]};
  const float* BH[3] = {(const float*)d_in[15], (const float*)d_in[17], (const float*)d_in[19]};
  const float* Wl1 = (const float*)d_in[20];
  const float* bl1 = (const float*)d_in[21];
  const float* Wl2 = (const float*)d_in[22];
  const float* bl2 = (const float*)d_in[23];
  float* out = (float*)d_out;

  // ---- workspace layout ----
  char* ws = (char*)d_ws;
  size_t off = 0;
  auto alloc = [&](size_t bytes) -> char* {
    char* p = ws + off;
    off = (off + bytes + 255) & ~(size_t)255;
    return p;
  };
  int*   row_start = (int*)alloc((size_t)(N + 1) * 4);
  int*   cnt       = (int*)alloc((size_t)N * 4);
  int*   esrc      = (int*)alloc((size_t)(E + N) * 4);
  int*   rank      = (int*)alloc((size_t)(E + N) * 4);
  int*   bsum      = (int*)alloc(256 * 4);
  float* als       = (float*)alloc((size_t)N * 3 * 4);
  float* ald       = (float*)alloc((size_t)N * 3 * 4);
  unsigned short* xb = (unsigned short*)alloc((size_t)N * F_IN * 2);   // x bf16
  unsigned short* P  = (unsigned short*)alloc((size_t)N * HE * 2);     // h (pi layout)
  unsigned short* Q  = (unsigned short*)alloc((size_t)N * HE * 2);     // agg out (pi layout)
  // weight slabs
  unsigned short* W1T  = (unsigned short*)alloc((size_t)F_IN * HE * 2);  // [384,128]
  unsigned short* W2T  = (unsigned short*)alloc((size_t)F_IN * HE * 2);
  unsigned short* W3T  = (unsigned short*)alloc((size_t)F_IN * HE * 2);
  unsigned short* WhPT[3];
  for (int l = 0; l < 3; ++l)
    WhPT[l] = (unsigned short*)alloc((size_t)HE * F_IN * 2);            // [128,384] K pi-permuted
  unsigned short* Wl1T = (unsigned short*)alloc((size_t)F_IN * 512 * 2); // [512,128]

  // ---- CSR by dst (counting sort; single atomic pass) ----
  hipMemsetAsync(cnt, 0, (size_t)N * 4, stream);
  k_hist<<<2048, 256, 0, stream>>>(ei, E, N, cnt, rank);
  int nsb = (N + 255) / 256;
  k_scan1<<<nsb, 256, 0, stream>>>(cnt, N, row_start, bsum);
  k_scan2<<<1, 256, 0, stream>>>(bsum, nsb);
  k_scan3<<<nsb, 256, 0, stream>>>(row_start, bsum, N);
  k_scatter<<<2048, 256, 0, stream>>>(ei, E, N, row_start, rank, esrc);

  // ---- dtype prep ----
  k_f2b4<<<(N * F_IN / 4 + 255) / 256, 256, 0, stream>>>(x, xb, N * F_IN / 4);
  k_w2bt<<<(F_IN * HE + 255) / 256, 256, 0, stream>>>(W[0], W1T, F_IN, HE);
  k_w2bt<<<(F_IN * HE + 255) / 256, 256, 0, stream>>>(W[1], W2T, F_IN, HE);
  k_w2bt<<<(F_IN * HE + 255) / 256, 256, 0, stream>>>(W[2], W3T, F_IN, HE);
  for (int l = 0; l < 3; ++l)
    k_w2btp<<<(HE * F_IN + 255) / 256, 256, 0, stream>>>(WH[l], WhPT[l], F_IN);
  k_w2bt<<<(F_IN * 512 + 255) / 256, 256, 0, stream>>>(Wl1, Wl1T, F_IN, 512);

  const int mb = (N + 127) / 128;
  const int nagg = (N + 1) / 2;

  // ---- layer 1: P = x@W1 (pi store) + als/ald; agg ----
  k_mgemm<128, true><<<dim3(mb, 3), 256, 0, stream>>>(xb, W1T, nullptr, P,
      AS[0], AD[0], als, ald, N, HE, 0);
  k_agg<<<nagg, 256, 0, stream>>>(P, als, ald, row_start, esrc, BB[0], Q, N);
  // ---- layer 2: fused (R1 = Q@Wh1+bh1) -> P = R1@W2 (pi) + als/ald; agg ----
  k_fused<3, false><<<mb, 256, 0, stream>>>(Q, WhPT[0], BH[0], W2T, nullptr, P,
      AS[1], AD[1], als, ald, nullptr, nullptr, nullptr, N, 0);
  k_agg<<<nagg, 256, 0, stream>>>(P, als, ald, row_start, esrc, BB[1], Q, N);
  // ---- layer 3 ----
  k_fused<3, false><<<mb, 256, 0, stream>>>(Q, WhPT[1], BH[1], W3T, nullptr, P,
      AS[2], AD[2], als, ald, nullptr, nullptr, nullptr, N, 0);
  k_agg<<<nagg, 256, 0, stream>>>(P, als, ald, row_start, esrc, BB[2], Q, N);
  // ---- MLP + head fused: (R3 = Q@Wh3+bh3) -> Z = elu(R3@Wl1+bl1) -> out = sigmoid(Z@Wl2+bl2) ----
  k_fused<4, true><<<mb, 256, 0, stream>>>(Q, WhPT[2], BH[2], Wl1T, bl1, nullptr,
      nullptr, nullptr, nullptr, nullptr, Wl2, bl2, out, N, 1);
}

// Round 12
// 585.691 us; speedup vs baseline: 2.3750x; 1.0711x over previous
//
#include <hip/hip_runtime.h>
#include <hip/hip_bf16.h>
#include <cstdint>
#include <cstddef>

// GuidedGNN: 3x GATConv(H=3, EMB=128, concat) + head transforms + MLP head.
// R10: revert k_agg to 1-wave/node (R9's 2-wave split regressed: barrier
// coupling > chain-halving for irregular degrees); self-loops handled inline
// in k_agg (out of CSR: fewer atomics, less gather traffic); all dtype prep
// + cnt-zeroing fused into one k_prep dispatch (21 -> 13 dispatches).
// Keeps: FINAL-fused MLP+head, fused dependent GEMMs, LDS-pipelined GEMM.

#define F_IN 128
#define EMB  128
#define NH   3
#define HE   (NH*EMB)   // 384
#define EXCAP 256       // per-wave LDS ex-cache entries (max real deg ~45)

typedef __attribute__((ext_vector_type(8))) short bf16x8;
typedef __attribute__((ext_vector_type(4))) float f32x4;

__device__ __forceinline__ float lrelu(float x){ return x > 0.f ? x : 0.2f * x; }
__device__ __forceinline__ float b2f(unsigned short u){ return __uint_as_float((unsigned)u << 16); }
__device__ __forceinline__ unsigned short f2b(float f){
  __hip_bfloat16 h = __float2bfloat16(f);
  return *reinterpret_cast<unsigned short*>(&h);
}
// channel permutation: orig c in [0,384) -> (c%128/2)*6 + head*2 + (c&1)
__device__ __forceinline__ int pi(int c){
  int hh = c >> 7, w = c & 127;
  return (w >> 1) * 6 + hh * 2 + (w & 1);
}
__device__ __forceinline__ void gload16(const unsigned short* g, unsigned short* l){
  __builtin_amdgcn_global_load_lds((const __attribute__((address_space(1))) unsigned int*)g,
                                   (__attribute__((address_space(3))) unsigned int*)l, 16, 0, 0);
}

struct u32x3 { unsigned x, y, z; };
struct f32x3 { float x, y, z; };

// ---------------- combined prep: x->bf16, weight transposes, cnt zero ----------------
#define S1 49152   // 128*384
#define S3 65536   // 128*512
__global__ void k_prep(const float* __restrict__ x, unsigned short* __restrict__ xb, int n4,
                       const float* __restrict__ W1, const float* __restrict__ W2,
                       const float* __restrict__ W3,
                       unsigned short* __restrict__ W1T, unsigned short* __restrict__ W2T,
                       unsigned short* __restrict__ W3T,
                       const float* __restrict__ Wh1, const float* __restrict__ Wh2,
                       const float* __restrict__ Wh3,
                       unsigned short* __restrict__ Wh1T, unsigned short* __restrict__ Wh2T,
                       unsigned short* __restrict__ Wh3T,
                       const float* __restrict__ Wl1, unsigned short* __restrict__ Wl1T,
                       int* __restrict__ cnt, int Nn){
  int i = blockIdx.x * 256 + threadIdx.x;
  if (i < n4){
    float4 v = reinterpret_cast<const float4*>(x)[i];
    unsigned short o[4] = {f2b(v.x), f2b(v.y), f2b(v.z), f2b(v.w)};
    *reinterpret_cast<uint2*>(&xb[i * 4]) = *reinterpret_cast<uint2*>(o);
    return;
  }
  i -= n4;
  if (i < 3 * S1){  // W1/W2/W3 [128,384] -> [384,128]
    const float* Wsrc = (i < S1) ? W1 : (i < 2 * S1) ? W2 : W3;
    unsigned short* Wdst = (i < S1) ? W1T : (i < 2 * S1) ? W2T : W3T;
    int j = i % S1;
    int r = j / HE, c = j % HE;
    Wdst[(size_t)c * F_IN + r] = f2b(Wsrc[j]);
    return;
  }
  i -= 3 * S1;
  if (i < 3 * S1){  // Wh1/2/3 [384,128] -> [128 cols][384] K pi-permuted
    const float* Wsrc = (i < S1) ? Wh1 : (i < 2 * S1) ? Wh2 : Wh3;
    unsigned short* Wdst = (i < S1) ? Wh1T : (i < 2 * S1) ? Wh2T : Wh3T;
    int j = i % S1;
    int r = j / F_IN, c = j % F_IN;
    Wdst[(size_t)c * HE + pi(r)] = f2b(Wsrc[j]);
    return;
  }
  i -= 3 * S1;
  if (i < S3){      // Wl1 [128,512] -> [512,128]
    int r = i / 512, c = i % 512;
    Wl1T[(size_t)c * F_IN + r] = f2b(Wl1[i]);
    return;
  }
  i -= S3;
  if (i < Nn) cnt[i] = 0;
}

// ---------------- CSR build (real edges only; self-loops handled in k_agg) ----------------
__global__ void k_hist(const int* __restrict__ ei, int E, int* __restrict__ cnt,
                       int* __restrict__ rank){
  for (int i = blockIdx.x * blockDim.x + threadIdx.x; i < E; i += gridDim.x * blockDim.x){
    int d = ei[E + i];
    rank[i] = atomicAdd(&cnt[d], 1);
  }
}

__global__ void k_scan1(const int* __restrict__ cnt, int n, int* __restrict__ rs, int* __restrict__ bsum){
  __shared__ int s[256];
  int t = threadIdx.x;
  int i = blockIdx.x * 256 + t;
  int v = (i < n) ? cnt[i] : 0;
  s[t] = v; __syncthreads();
  for (int off = 1; off < 256; off <<= 1){
    int x = (t >= off) ? s[t - off] : 0;
    __syncthreads();
    s[t] += x;
    __syncthreads();
  }
  if (i < n) rs[i + 1] = s[t];
  if (t == 255) bsum[blockIdx.x] = s[255];
}

__global__ void k_scan2(int* __restrict__ bsum, int nb){
  __shared__ int s[256];
  int t = threadIdx.x;
  int v = (t < nb) ? bsum[t] : 0;
  s[t] = v; __syncthreads();
  for (int off = 1; off < 256; off <<= 1){
    int x = (t >= off) ? s[t - off] : 0;
    __syncthreads();
    s[t] += x;
    __syncthreads();
  }
  if (t < nb) bsum[t] = (t > 0) ? s[t - 1] : 0;  // exclusive
}

__global__ void k_scan3(int* __restrict__ rs, const int* __restrict__ bsum, int n){
  int i = blockIdx.x * 256 + threadIdx.x;
  if (i < n) rs[i + 1] += bsum[blockIdx.x];
  if (i == 0) rs[0] = 0;
}

__global__ void k_scatter(const int* __restrict__ ei, int E, const int* __restrict__ rs,
                          const int* __restrict__ rank, int* __restrict__ esrc){
  for (int i = blockIdx.x * blockDim.x + threadIdx.x; i < E; i += gridDim.x * blockDim.x){
    esrc[rs[ei[E + i]] + rank[i]] = ei[i];
  }
}

// ---------------- LDS-pipelined MFMA GEMM (layer-1 only) ----------------
template<int K, bool PERM>
__global__ __launch_bounds__(256, 2) void k_mgemm(const unsigned short* __restrict__ A,
                                                  const unsigned short* __restrict__ BT,
                                                  const float* __restrict__ bias,
                                                  unsigned short* __restrict__ C,
                                                  const float* __restrict__ a_s,
                                                  const float* __restrict__ a_d,
                                                  float* __restrict__ als, float* __restrict__ ald,
                                                  int M, int Ncols, int act){
  __shared__ unsigned short sA[2][8192];   // [buf][128 rows x 64 k] swizzled
  __shared__ unsigned short sB[2][8192];
  const int lane = threadIdx.x & 63;
  const int wave = threadIdx.x >> 6;
  const int brow = blockIdx.x * 128;
  const int bcol = blockIdx.y * 128;
  const int wr = wave >> 1, wc = wave & 1;
  const int r15 = lane & 15;
  const int kg = (lane >> 4) * 8;
  const int row0 = brow + wr * 64;
  const int col0 = bcol + wc * 64;
  f32x4 acc[4][4] = {};

  const int cbase = wave * 64 + lane;
  auto stage = [&](int buf, int kt){
#pragma unroll
    for (int j = 0; j < 4; ++j){
      int c = cbase + j * 256;
      int r = c >> 3;
      int k0 = ((c ^ r) & 7) * 8;
      int ldsoff = (wave * 64 + j * 256) * 8;   // wave-uniform; HW adds lane*16B
      int ra = brow + r; if (ra >= M) ra = M - 1;
      gload16(&A[(size_t)ra * K + kt + k0], &sA[buf][ldsoff]);
      gload16(&BT[(size_t)(bcol + r) * K + kt + k0], &sB[buf][ldsoff]);
    }
  };
  auto compute = [&](int buf){
#pragma unroll
    for (int ks = 0; ks < 2; ++ks){
      bf16x8 a[4], b[4];
#pragma unroll
      for (int m = 0; m < 4; ++m){
        int row = wr * 64 + m * 16 + r15;
        int idx = (row * 64 + ks * 32 + kg) ^ ((row & 7) << 3);
        a[m] = *reinterpret_cast<const bf16x8*>(&sA[buf][idx]);
      }
#pragma unroll
      for (int n = 0; n < 4; ++n){
        int row = wc * 64 + n * 16 + r15;
        int idx = (row * 64 + ks * 32 + kg) ^ ((row & 7) << 3);
        b[n] = *reinterpret_cast<const bf16x8*>(&sB[buf][idx]);
      }
#pragma unroll
      for (int m = 0; m < 4; ++m)
#pragma unroll
        for (int n = 0; n < 4; ++n)
          acc[m][n] = __builtin_amdgcn_mfma_f32_16x16x32_bf16(a[m], b[n], acc[m][n], 0, 0, 0);
    }
  };

  constexpr int NK = K / 64;
  stage(0, 0);
  int cur = 0;
#pragma unroll
  for (int t = 0; t < NK; ++t){
    __syncthreads();
    if (t + 1 < NK) stage(cur ^ 1, (t + 1) * 64);
    compute(cur);
    cur ^= 1;
  }

#pragma unroll
  for (int m = 0; m < 4; ++m){
#pragma unroll
    for (int n = 0; n < 4; ++n){
      int c = col0 + n * 16 + r15;
      float bsv = bias ? bias[c] : 0.f;
      int cs = PERM ? pi(c) : c;
#pragma unroll
      for (int q = 0; q < 4; ++q){
        int r = row0 + m * 16 + (lane >> 4) * 4 + q;
        if (r < M){
          float v = acc[m][n][q] + bsv;
          if (act) v = (v > 0.f) ? v : expm1f(v);
          C[(size_t)r * Ncols + cs] = f2b(v);
        }
      }
    }
  }
  if (a_s){
    __syncthreads();
    float* sred = reinterpret_cast<float*>(&sA[0][0]);   // [2][128]
    float* dred = sred + 256;
    const int head = blockIdx.y;
    const int cin = wc * 64;
    float asv[4], adv[4];
#pragma unroll
    for (int n = 0; n < 4; ++n){
      int c = head * EMB + cin + n * 16 + r15;
      asv[n] = a_s[c]; adv[n] = a_d[c];
    }
#pragma unroll
    for (int m = 0; m < 4; ++m){
#pragma unroll
      for (int q = 0; q < 4; ++q){
        float ps = acc[m][0][q] * asv[0] + acc[m][1][q] * asv[1]
                 + acc[m][2][q] * asv[2] + acc[m][3][q] * asv[3];
        float pd = acc[m][0][q] * adv[0] + acc[m][1][q] * adv[1]
                 + acc[m][2][q] * adv[2] + acc[m][3][q] * adv[3];
#pragma unroll
        for (int off = 1; off < 16; off <<= 1){
          ps += __shfl_xor(ps, off);
          pd += __shfl_xor(pd, off);
        }
        if (r15 == 0){
          int rowl = wr * 64 + m * 16 + (lane >> 4) * 4 + q;
          sred[wc * 128 + rowl] = ps;
          dred[wc * 128 + rowl] = pd;
        }
      }
    }
    __syncthreads();
    if (threadIdx.x < 128){
      int rowl = threadIdx.x;
      int r = brow + rowl;
      if (r < M){
        als[(size_t)r * 3 + head] = sred[rowl] + sred[128 + rowl];
        ald[(size_t)r * 3 + head] = dred[rowl] + dred[128 + rowl];
      }
    }
  }
}

// ---------------- fused dependent GEMM ----------------
// T = A@B1^T + bias1 (K=384, LDS dbuf) kept in LDS; then per 128-col chunk
// C_chunk = T@B2_chunk^T (+bias2)(+elu). NCH==3: pi store + als/ald epilogue.
// FINAL: no C store; per-chunk dot with w2 accumulated in LDS -> sigmoid out.
template<int NCH, bool FINAL>
__global__ __launch_bounds__(256, 2) void k_fused(const unsigned short* __restrict__ A,
                                                  const unsigned short* __restrict__ B1,
                                                  const float* __restrict__ bias1,
                                                  const unsigned short* __restrict__ B2,
                                                  const float* __restrict__ bias2,
                                                  unsigned short* __restrict__ C,
                                                  const float* __restrict__ a_s,
                                                  const float* __restrict__ a_d,
                                                  float* __restrict__ als, float* __restrict__ ald,
                                                  const float* __restrict__ w2,
                                                  const float* __restrict__ b2s,
                                                  float* __restrict__ outp,
                                                  int M, int act2){
  __shared__ unsigned short sA[2][8192];   // stage-1 A dbuf; then T[128][128] swizzled
  __shared__ unsigned short sB[2][8192];   // stage-1 B dbuf; then B2 chunk (32KB)
  __shared__ float sred[2][128];
  __shared__ float dred[2][128];
  __shared__ float zsum[2][128];
  const int lane = threadIdx.x & 63;
  const int wave = threadIdx.x >> 6;
  const int brow = blockIdx.x * 128;
  const int wr = wave >> 1, wc = wave & 1;
  const int r15 = lane & 15;
  const int kg = (lane >> 4) * 8;
  const int qrow = (lane >> 4) * 4;
  f32x4 acc[4][4] = {};
  const int cbase = wave * 64 + lane;

  if (FINAL && threadIdx.x < 128){ zsum[0][threadIdx.x] = 0.f; zsum[1][threadIdx.x] = 0.f; }

  // ---- stage 1: T = A(pi)@B1^T, K=384, BK=64 double-buffered ----
  auto stage1 = [&](int buf, int kt){
#pragma unroll
    for (int j = 0; j < 4; ++j){
      int c = cbase + j * 256;
      int r = c >> 3;
      int k0 = ((c ^ r) & 7) * 8;
      int ldsoff = (wave * 64 + j * 256) * 8;
      int ra = brow + r; if (ra >= M) ra = M - 1;
      gload16(&A[(size_t)ra * HE + kt + k0], &sA[buf][ldsoff]);
      gload16(&B1[(size_t)r * HE + kt + k0], &sB[buf][ldsoff]);
    }
  };
  stage1(0, 0);
  int cur = 0;
#pragma unroll
  for (int t = 0; t < 6; ++t){
    __syncthreads();
    if (t + 1 < 6) stage1(cur ^ 1, (t + 1) * 64);
#pragma unroll
    for (int ks = 0; ks < 2; ++ks){
      bf16x8 a[4], b[4];
#pragma unroll
      for (int m = 0; m < 4; ++m){
        int row = wr * 64 + m * 16 + r15;
        int idx = (row * 64 + ks * 32 + kg) ^ ((row & 7) << 3);
        a[m] = *reinterpret_cast<const bf16x8*>(&sA[cur][idx]);
      }
#pragma unroll
      for (int n = 0; n < 4; ++n){
        int row = wc * 64 + n * 16 + r15;
        int idx = (row * 64 + ks * 32 + kg) ^ ((row & 7) << 3);
        b[n] = *reinterpret_cast<const bf16x8*>(&sB[cur][idx]);
      }
#pragma unroll
      for (int m = 0; m < 4; ++m)
#pragma unroll
        for (int n = 0; n < 4; ++n)
          acc[m][n] = __builtin_amdgcn_mfma_f32_16x16x32_bf16(a[m], b[n], acc[m][n], 0, 0, 0);
    }
    cur ^= 1;
  }
  __syncthreads();   // all stage-1 LDS reads done
  unsigned short* T = &sA[0][0];
#pragma unroll
  for (int m = 0; m < 4; ++m){
#pragma unroll
    for (int n = 0; n < 4; ++n){
      int col = wc * 64 + n * 16 + r15;
      float bv = bias1[col];
#pragma unroll
      for (int q = 0; q < 4; ++q){
        int row = wr * 64 + m * 16 + qrow + q;
        T[(row * 128 + col) ^ ((row & 7) << 3)] = f2b(acc[m][n][q] + bv);
      }
    }
  }
  __syncthreads();   // T visible

  // ---- stage 2: per 128-col chunk ----
  unsigned short* Bs = &sB[0][0];
#pragma unroll
  for (int cc = 0; cc < NCH; ++cc){
    if (cc > 0) __syncthreads();
#pragma unroll
    for (int j = 0; j < 8; ++j){
      int c = cbase + j * 256;     // 128 rows x 16 chunks (CPR=16)
      int r = c >> 4;
      int cr = c & 15;
      int k0 = ((cr & 8) | ((cr ^ r) & 7)) * 8;
      int ldsoff = (wave * 64 + j * 256) * 8;
      gload16(&B2[(size_t)(cc * 128 + r) * 128 + k0], &Bs[ldsoff]);
    }
    __syncthreads();
#pragma unroll
    for (int m = 0; m < 4; ++m)
#pragma unroll
      for (int n = 0; n < 4; ++n)
        acc[m][n] = (f32x4){0.f, 0.f, 0.f, 0.f};
#pragma unroll
    for (int ks = 0; ks < 4; ++ks){
      bf16x8 a[4], b[4];
#pragma unroll
      for (int m = 0; m < 4; ++m){
        int row = wr * 64 + m * 16 + r15;
        int idx = (row * 128 + ks * 32 + kg) ^ ((row & 7) << 3);
        a[m] = *reinterpret_cast<const bf16x8*>(&T[idx]);
      }
#pragma unroll
      for (int n = 0; n < 4; ++n){
        int row = wc * 64 + n * 16 + r15;
        int idx = (row * 128 + ks * 32 + kg) ^ ((row & 7) << 3);
        b[n] = *reinterpret_cast<const bf16x8*>(&Bs[idx]);
      }
#pragma unroll
      for (int m = 0; m < 4; ++m)
#pragma unroll
        for (int n = 0; n < 4; ++n)
          acc[m][n] = __builtin_amdgcn_mfma_f32_16x16x32_bf16(a[m], b[n], acc[m][n], 0, 0, 0);
    }
    if (FINAL){
      float w2v[4];
#pragma unroll
      for (int n = 0; n < 4; ++n)
        w2v[n] = w2[cc * 128 + wc * 64 + n * 16 + r15];
#pragma unroll
      for (int m = 0; m < 4; ++m){
#pragma unroll
        for (int q = 0; q < 4; ++q){
          float p = 0.f;
#pragma unroll
          for (int n = 0; n < 4; ++n){
            float v = acc[m][n][q] + bias2[cc * 128 + wc * 64 + n * 16 + r15];
            v = (v > 0.f) ? v : expm1f(v);
            p += v * w2v[n];
          }
#pragma unroll
          for (int off = 1; off < 16; off <<= 1) p += __shfl_xor(p, off);
          if (r15 == 0) zsum[wc][wr * 64 + m * 16 + qrow + q] += p;
        }
      }
    } else {
#pragma unroll
      for (int m = 0; m < 4; ++m){
#pragma unroll
        for (int n = 0; n < 4; ++n){
          int cglob = cc * 128 + wc * 64 + n * 16 + r15;
          float bv = bias2 ? bias2[cglob] : 0.f;
          int cs = (NCH == 3) ? pi(cglob) : cglob;
          const int ncols = (NCH == 3) ? HE : 512;
#pragma unroll
          for (int q = 0; q < 4; ++q){
            int rg = brow + wr * 64 + m * 16 + qrow + q;
            if (rg < M){
              float v = acc[m][n][q] + bv;
              if (act2) v = (v > 0.f) ? v : expm1f(v);
              C[(size_t)rg * ncols + cs] = f2b(v);
            }
          }
        }
      }
    }
    if (a_s){
      const int cin = wc * 64;
      float asv[4], adv[4];
#pragma unroll
      for (int n = 0; n < 4; ++n){
        int cglob = cc * 128 + cin + n * 16 + r15;
        asv[n] = a_s[cglob]; adv[n] = a_d[cglob];
      }
#pragma unroll
      for (int m = 0; m < 4; ++m){
#pragma unroll
        for (int q = 0; q < 4; ++q){
          float ps = acc[m][0][q] * asv[0] + acc[m][1][q] * asv[1]
                   + acc[m][2][q] * asv[2] + acc[m][3][q] * asv[3];
          float pd = acc[m][0][q] * adv[0] + acc[m][1][q] * adv[1]
                   + acc[m][2][q] * adv[2] + acc[m][3][q] * adv[3];
#pragma unroll
          for (int off = 1; off < 16; off <<= 1){
            ps += __shfl_xor(ps, off);
            pd += __shfl_xor(pd, off);
          }
          if (r15 == 0){
            int rowl = wr * 64 + m * 16 + qrow + q;
            sred[wc][rowl] = ps;
            dred[wc][rowl] = pd;
          }
        }
      }
      __syncthreads();
      if (threadIdx.x < 128){
        int rowl = threadIdx.x;
        int rg = brow + rowl;
        if (rg < M){
          als[(size_t)rg * 3 + cc] = sred[0][rowl] + sred[1][rowl];
          ald[(size_t)rg * 3 + cc] = dred[0][rowl] + dred[1][rowl];
        }
      }
    }
  }
  if (FINAL){
    __syncthreads();
    if (threadIdx.x < 128){
      int rg = brow + threadIdx.x;
      if (rg < M){
        float z = zsum[0][threadIdx.x] + zsum[1][threadIdx.x] + b2s[0];
        outp[rg] = 1.f / (1.f + __expf(-z));
      }
    }
  }
}

// ---------------- GAT aggregation (1 wave/node, barrier-free) + inline self-loop ----
// pass A: lane-parallel exp over real in-edges + LDS ex-cache; self term added
// uniformly after reduce. pass B: serial gather of h rows, unrolled x4.
__global__ __launch_bounds__(256) void k_agg(const unsigned short* __restrict__ h,
                                             const float* __restrict__ als,
                                             const float* __restrict__ ald,
                                             const int* __restrict__ rs, const int* __restrict__ esrc,
                                             const float* __restrict__ bias,
                                             unsigned short* __restrict__ out, int Nn){
  __shared__ float exs[4][EXCAP * 3];      // 12 KB: per-wave ex cache
  int wave = threadIdx.x >> 6;
  int n = blockIdx.x * 4 + wave;
  int lane = threadIdx.x & 63;
  if (n >= Nn) return;
  int start = rs[n], end = rs[n + 1];
  f32x3 adn = *reinterpret_cast<const f32x3*>(&ald[(size_t)n * 3]);
  f32x3 asn = *reinterpret_cast<const f32x3*>(&als[(size_t)n * 3]);
  float es0 = __expf(lrelu(asn.x + adn.x));   // self-loop term (wave-uniform)
  float es1 = __expf(lrelu(asn.y + adn.y));
  float es2 = __expf(lrelu(asn.z + adn.z));
  float d0 = 0.f, d1 = 0.f, d2 = 0.f;
  for (int i = start + lane; i < end; i += 64){
    int s = esrc[i];
    f32x3 as = *reinterpret_cast<const f32x3*>(&als[(size_t)s * 3]);
    float e0 = __expf(lrelu(as.x + adn.x));
    float e1 = __expf(lrelu(as.y + adn.y));
    float e2 = __expf(lrelu(as.z + adn.z));
    d0 += e0; d1 += e1; d2 += e2;
    int j = i - start;
    if (j < EXCAP){
      exs[wave][j * 3 + 0] = e0;
      exs[wave][j * 3 + 1] = e1;
      exs[wave][j * 3 + 2] = e2;
    }
  }
  for (int off = 32; off; off >>= 1){
    d0 += __shfl_xor(d0, off);
    d1 += __shfl_xor(d1, off);
    d2 += __shfl_xor(d2, off);
  }
  d0 += es0; d1 += es1; d2 += es2;   // self term, uniform across lanes
  float iv[3] = {1.f / (d0 + 1e-16f), 1.f / (d1 + 1e-16f), 1.f / (d2 + 1e-16f)};
  // init acc with self contribution (contiguous wave-wide row read)
  const int l3 = lane * 3;
  float acc[6];
  {
    u32x3 v = *reinterpret_cast<const u32x3*>(reinterpret_cast<const unsigned*>(h + (size_t)n * HE) + l3);
    acc[0] = es0 * b2f((unsigned short)v.x);
    acc[1] = es0 * b2f((unsigned short)(v.x >> 16));
    acc[2] = es1 * b2f((unsigned short)v.y);
    acc[3] = es1 * b2f((unsigned short)(v.y >> 16));
    acc[4] = es2 * b2f((unsigned short)v.z);
    acc[5] = es2 * b2f((unsigned short)(v.z >> 16));
  }
  const float* exw = exs[wave];
  int i = start;
  int nfast = end;
  if (end - start > EXCAP) nfast = start + EXCAP;
  for (; i + 3 < nfast; i += 4){
    u32x3 hv[4]; f32x3 ev[4];
#pragma unroll
    for (int u = 0; u < 4; ++u){
      int s = esrc[i + u];
      hv[u] = *reinterpret_cast<const u32x3*>(reinterpret_cast<const unsigned*>(h + (size_t)s * HE) + l3);
      int j = (i + u - start) * 3;
      ev[u].x = exw[j]; ev[u].y = exw[j + 1]; ev[u].z = exw[j + 2];
    }
#pragma unroll
    for (int u = 0; u < 4; ++u){
      acc[0] += ev[u].x * b2f((unsigned short)hv[u].x);
      acc[1] += ev[u].x * b2f((unsigned short)(hv[u].x >> 16));
      acc[2] += ev[u].y * b2f((unsigned short)hv[u].y);
      acc[3] += ev[u].y * b2f((unsigned short)(hv[u].y >> 16));
      acc[4] += ev[u].z * b2f((unsigned short)hv[u].z);
      acc[5] += ev[u].z * b2f((unsigned short)(hv[u].z >> 16));
    }
  }
  for (; i < end; ++i){
    int j = i - start;
    int s = esrc[i];
    float e0, e1, e2;
    if (j < EXCAP){
      e0 = exw[j * 3]; e1 = exw[j * 3 + 1]; e2 = exw[j * 3 + 2];
    } else {
      f32x3 as = *reinterpret_cast<const f32x3*>(&als[(size_t)s * 3]);
      e0 = __expf(lrelu(as.x + adn.x));
      e1 = __expf(lrelu(as.y + adn.y));
      e2 = __expf(lrelu(as.z + adn.z));
    }
    u32x3 v = *reinterpret_cast<const u32x3*>(reinterpret_cast<const unsigned*>(h + (size_t)s * HE) + l3);
    acc[0] += e0 * b2f((unsigned short)v.x);
    acc[1] += e0 * b2f((unsigned short)(v.x >> 16));
    acc[2] += e1 * b2f((unsigned short)v.y);
    acc[3] += e1 * b2f((unsigned short)(v.y >> 16));
    acc[4] += e2 * b2f((unsigned short)v.z);
    acc[5] += e2 * b2f((unsigned short)(v.z >> 16));
  }
  unsigned ov[3];
#pragma unroll
  for (int hh = 0; hh < 3; ++hh){
    int ch = 128 * hh + 2 * lane;
    float v0 = acc[2 * hh] * iv[hh] + bias[ch];
    float v1 = acc[2 * hh + 1] * iv[hh] + bias[ch + 1];
    v0 = (v0 > 0.f) ? v0 : expm1f(v0);
    v1 = (v1 > 0.f) ? v1 : expm1f(v1);
    ov[hh] = (unsigned)f2b(v0) | ((unsigned)f2b(v1) << 16);
  }
  unsigned* orow = reinterpret_cast<unsigned*>(out + (size_t)n * HE) + l3;
  *reinterpret_cast<u32x3*>(orow) = *reinterpret_cast<u32x3*>(ov);
}

extern "C" void kernel_launch(void* const* d_in, const int* in_sizes, int n_in,
                              void* d_out, int out_size, void* d_ws, size_t ws_size,
                              hipStream_t stream){
  const float* x   = (const float*)d_in[0];
  const int*   ei  = (const int*)d_in[1];
  const int N = in_sizes[0] / F_IN;
  const int E = in_sizes[1] / 2;
  const float* W[3]  = {(const float*)d_in[2], (const float*)d_in[6], (const float*)d_in[10]};
  const float* AS[3] = {(const float*)d_in[3], (const float*)d_in[7], (const float*)d_in[11]};
  const float* AD[3] = {(const float*)d_in[4], (const float*)d_in[8], (const float*)d_in[12]};
  const float* BB[3] = {(const float*)d_in[5], (const float*)d_in[9], (const float*)d_in[13]};
  const float* WH[3] = {(const float*)d_in[14], (const float*)d_in[16], (const float*)d_in[18]};
  const float* BH[3] = {(const float*)d_in[15], (const float*)d_in[17], (const float*)d_in[19]};
  const float* Wl1 = (const float*)d_in[20];
  const float* bl1 = (const float*)d_in[21];
  const float* Wl2 = (const float*)d_in[22];
  const float* bl2 = (const float*)d_in[23];
  float* out = (float*)d_out;

  // ---- workspace layout ----
  char* ws = (char*)d_ws;
  size_t off = 0;
  auto alloc = [&](size_t bytes) -> char* {
    char* p = ws + off;
    off = (off + bytes + 255) & ~(size_t)255;
    return p;
  };
  int*   row_start = (int*)alloc((size_t)(N + 1) * 4);
  int*   cnt       = (int*)alloc((size_t)N * 4);
  int*   esrc      = (int*)alloc((size_t)E * 4);
  int*   rank      = (int*)alloc((size_t)E * 4);
  int*   bsum      = (int*)alloc(256 * 4);
  float* als       = (float*)alloc((size_t)N * 3 * 4);
  float* ald       = (float*)alloc((size_t)N * 3 * 4);
  unsigned short* xb = (unsigned short*)alloc((size_t)N * F_IN * 2);   // x bf16
  unsigned short* P  = (unsigned short*)alloc((size_t)N * HE * 2);     // h (pi layout)
  unsigned short* Q  = (unsigned short*)alloc((size_t)N * HE * 2);     // agg out (pi layout)
  // weight slabs
  unsigned short* W1T  = (unsigned short*)alloc((size_t)F_IN * HE * 2);  // [384,128]
  unsigned short* W2T  = (unsigned short*)alloc((size_t)F_IN * HE * 2);
  unsigned short* W3T  = (unsigned short*)alloc((size_t)F_IN * HE * 2);
  unsigned short* WhPT[3];
  for (int l = 0; l < 3; ++l)
    WhPT[l] = (unsigned short*)alloc((size_t)HE * F_IN * 2);            // [128,384] K pi-permuted
  unsigned short* Wl1T = (unsigned short*)alloc((size_t)F_IN * 512 * 2); // [512,128]

  // ---- single prep dispatch: x->bf16, all weight transposes, cnt zero ----
  const int n4 = N * F_IN / 4;
  const int prep_total = n4 + 6 * S1 + S3 + N;
  k_prep<<<(prep_total + 255) / 256, 256, 0, stream>>>(
      x, xb, n4, W[0], W[1], W[2], W1T, W2T, W3T,
      WH[0], WH[1], WH[2], WhPT[0], WhPT[1], WhPT[2], Wl1, Wl1T, cnt, N);

  // ---- CSR by dst (real edges only; single atomic pass) ----
  k_hist<<<2048, 256, 0, stream>>>(ei, E, cnt, rank);
  int nsb = (N + 255) / 256;
  k_scan1<<<nsb, 256, 0, stream>>>(cnt, N, row_start, bsum);
  k_scan2<<<1, 256, 0, stream>>>(bsum, nsb);
  k_scan3<<<nsb, 256, 0, stream>>>(row_start, bsum, N);
  k_scatter<<<2048, 256, 0, stream>>>(ei, E, row_start, rank, esrc);

  const int mb = (N + 127) / 128;
  const int nwave = (N + 3) / 4;

  // ---- layer 1: P = x@W1 (pi store) + als/ald; agg ----
  k_mgemm<128, true><<<dim3(mb, 3), 256, 0, stream>>>(xb, W1T, nullptr, P,
      AS[0], AD[0], als, ald, N, HE, 0);
  k_agg<<<nwave, 256, 0, stream>>>(P, als, ald, row_start, esrc, BB[0], Q, N);
  // ---- layer 2: fused (R1 = Q@Wh1+bh1) -> P = R1@W2 (pi) + als/ald; agg ----
  k_fused<3, false><<<mb, 256, 0, stream>>>(Q, WhPT[0], BH[0], W2T, nullptr, P,
      AS[1], AD[1], als, ald, nullptr, nullptr, nullptr, N, 0);
  k_agg<<<nwave, 256, 0, stream>>>(P, als, ald, row_start, esrc, BB[1], Q, N);
  // ---- layer 3 ----
  k_fused<3, false><<<mb, 256, 0, stream>>>(Q, WhPT[1], BH[1], W3T, nullptr, P,
      AS[2], AD[2], als, ald, nullptr, nullptr, nullptr, N, 0);
  k_agg<<<nwave, 256, 0, stream>>>(P, als, ald, row_start, esrc, BB[2], Q, N);
  // ---- MLP + head fused ----
  k_fused<4, true><<<mb, 256, 0, stream>>>(Q, WhPT[2], BH[2], Wl1T, bl1, nullptr,
      nullptr, nullptr, nullptr, nullptr, Wl2, bl2, out, N, 1);
}